// Round 21
// baseline (2614.326 us; speedup 1.0000x reference)
//
#include <hip/hip_runtime.h>
#include <hip/hip_bf16.h>

#define CB 256      // batch
#define CN 256      // nodes
#define CK 3        // children per node
#define CE 256      // embedding dim
#define CH 256      // hidden dim
#define CG_ 1536    // gates = 6*CH
#define KTOT 1024   // E + K*H
#define ROWS 32     // rows per chunk (r19-verified geometry)
#define ASTR 1032   // A row stride in u16 (2064 B)

typedef __attribute__((ext_vector_type(8))) short short8v;          // 8 bf16
typedef __attribute__((ext_vector_type(4))) float float4v;          // MFMA C/D
typedef __attribute__((ext_vector_type(4))) unsigned int uint4v;
typedef __attribute__((ext_vector_type(4))) unsigned short ushort4v;
typedef unsigned int u32;
typedef unsigned long long u64;
typedef unsigned short u16;

__device__ __forceinline__ u16 f2bfu(float v) {
    __hip_bfloat16 h = __float2bfloat16(v);
    return __builtin_bit_cast(u16, h);
}
__device__ __forceinline__ float bfu2f(u16 u) {
    __hip_bfloat16 h = __builtin_bit_cast(__hip_bfloat16, u);
    return __bfloat162float(h);
}

// ---------------------------------------------------------------------------
// Prep (verified r17-r20): split W = [Wx_w ; Uh_w] into bf16 hi/lo planes in
// MFMA-FRAGMENT order [tile(16 gate cols)][ci][lane][8] — wave B-load = 1 KB
// contiguous.
// ---------------------------------------------------------------------------
__global__ __launch_bounds__(256) void prep_w(
    const float* __restrict__ Wx_w, const float* __restrict__ Uh_w,
    u16* __restrict__ Whi, u16* __restrict__ Wlo)
{
    const int g    = blockIdx.x;           // gate col 0..1535
    const int tile = g >> 4;
    const int gl   = g & 15;
    for (int k = threadIdx.x; k < KTOT; k += 256) {
        float w = (k < CE) ? Wx_w[(size_t)k * CG_ + g]
                           : Uh_w[(size_t)(k - CE) * CG_ + g];
        u16 hi = f2bfu(w);
        u16 lo = f2bfu(w - bfu2f(hi));
        int ci = k >> 5, kr = k & 31, lq = kr >> 3, j = kr & 7;
        size_t idx = ((size_t)(tile * 32 + ci) * 64 + lq * 16 + gl) * 8 + j;
        Whi[idx] = hi;
        Wlo[idx] = lo;
    }
}

// ---------------------------------------------------------------------------
// Level schedule build (verified r14-r20, incl. the 0xFFFF-collision fix).
// ---------------------------------------------------------------------------
__global__ __launch_bounds__(256) void build_sched(
    const int* __restrict__ children,
    u16* __restrict__ wl,             // [65536] (b<<8)|t
    u32* __restrict__ lvl_start,      // [256]
    u32* __restrict__ lvl_cnt,        // [256]
    u32* __restrict__ nlev)           // [1]
{
    __shared__ unsigned char lvl[CB][CN];   // 64 KB
    __shared__ u32 cnt[CN];
    __shared__ u32 pos[CN];
    const int b = threadIdx.x;

    for (int t = 0; t < CN; ++t) {
        int lv = 0;
        #pragma unroll
        for (int k = 0; k < CK; ++k) {
            int raw = children[((size_t)b * CN + t) * CK + k];
            if (raw < t) { int cl = (int)lvl[b][raw] + 1; if (cl > lv) lv = cl; }
        }
        lvl[b][t] = (unsigned char)lv;
    }
    cnt[b] = 0;
    __syncthreads();
    for (int t = 0; t < CN; ++t) atomicAdd(&cnt[lvl[b][t]], 1u);
    __syncthreads();
    if (b == 0) {
        u32 acc = 0, nl = 0;
        for (int L = 0; L < CN; ++L) {
            pos[L] = acc;
            if (cnt[L]) nl = (u32)L + 1;
            acc += cnt[L];
        }
        *nlev = nl;
    }
    __syncthreads();
    lvl_cnt[b]   = cnt[b];
    lvl_start[b] = pos[b];
    __syncthreads();
    for (int t = 0; t < CN; ++t) {
        int L = lvl[b][t];
        u32 p = atomicAdd(&pos[L], 1u);
        wl[p] = (u16)((b << 8) | t);
    }
}

// ---------------------------------------------------------------------------
// r21 scan: r19 geometry (ROWS=32, S=2) with two T_chunk cuts.
// Lesson from r20: the limiter is per-level LATENCY (most levels fill only a
// fraction of the 128 sub-groups -> each level ~ one T_chunk), so optimize
// T_chunk, not aggregate bytes. Changes vs r19:
//  1. A staged into SEPARATE Ahi/Alo u16 LDS arrays (packed h_pk split once
//     during staging) -> MFMA loop is direct ds_read_b128, removing ~1280
//     VALU unpack ops/wave/chunk (the bulk of VALUBusy).
//  2. 1024 threads = 16 waves = (ctq 0..7) x (rg 0..1), 4 waves/SIMD: per-
//     wave MFMA halves and B/LDS latency is hidden twice as deep.
// accH/accL separate chains (r19 ILP). Schedule/sc1/flag-barrier identical.
// ---------------------------------------------------------------------------
__global__ __launch_bounds__(1024, 4) void tree_scan_lvl(
    const int* __restrict__ node_ids,          // [B][N]
    const int* __restrict__ children,          // [B][N][K]
    const float* __restrict__ emb,             // [V][E]
    const u16* __restrict__ Whi,               // fragment-ordered
    const u16* __restrict__ Wlo,               // fragment-ordered
    const float* __restrict__ Wx_b,            // [G]
    const float* __restrict__ Uh_b,            // [K][G]
    u32* __restrict__ h_pk,                    // [N][B][H] u32 (hi16|lo16)
    float* __restrict__ c_s,                   // [N][B][H] f32
    u32* __restrict__ flags,                   // [256*16], zeroed per call
    const u16* __restrict__ wl,                // [65536]
    const u32* __restrict__ lvl_start,         // [256]
    const u32* __restrict__ lvl_cnt,           // [256]
    const u32* __restrict__ nlev_p,            // [1]
    float* __restrict__ out)                   // [B][H] f32
{
    const int tid = threadIdx.x;
    const int bid = blockIdx.x;
    const int xcd   = bid & 7;
    const int slice = xcd >> 2;                          // 0..1 (4 XCDs each)
    const int sub   = ((bid >> 3) << 2) | (bid & 3);     // 0..127
    const int hh0   = slice * 128;

    __shared__ u16   Ahi[ROWS][ASTR];          // 66,048 B
    __shared__ u16   Alo[ROWS][ASTR];          // 66,048 B
    __shared__ int   nid[ROWS], brow[ROWS], trow[ROWS];
    __shared__ unsigned char rval[ROWS];
    __shared__ float msk[ROWS][3];
    __shared__ int   cix[ROWS][3];

    const int wv    = tid >> 6;                // 0..15
    const int ctq   = wv & 7;                  // col-tile
    const int rg    = wv >> 3;                 // row-group
    const int l     = tid & 63;
    const int lan15 = l & 15;
    const int k8    = (l >> 4) * 8;            // k-offset inside A row (u16)
    const int hcol  = hh0 + ctq * 16 + lan15;  // this lane's h column
    const int arow  = rg * 16 + lan15;         // this lane's A row

    // fragment-plane bases: tile = q*16 + slice*8 + ctq
    u32 bb[6];
    #pragma unroll
    for (int q = 0; q < 6; ++q)
        bb[q] = (u32)(q * 16 + slice * 8 + ctq) * 16384u + (u32)l * 8u;

    const u32 NL = *nlev_p;

    for (u32 L = 0; L < NL; ++L) {
        const u32 lcnt   = lvl_cnt[L];
        const u32 lst    = lvl_start[L];
        const u32 nchunk = (lcnt + ROWS - 1) / ROWS;

        for (u32 ck = sub; ck < nchunk; ck += 128) {
            if (tid < ROWS) {
                u32 i = ck * ROWS + (u32)tid;
                int valid = (i < lcnt);
                u16 e = valid ? wl[lst + i] : (u16)0;
                rval[tid] = (unsigned char)valid;
                int b_ = valid ? (e >> 8) : 0;
                int t_ = valid ? (e & 0xFF) : 0;
                brow[tid] = b_;
                trow[tid] = t_;
                nid[tid]  = node_ids[(size_t)b_ * CN + t_];
            }
            if (tid < ROWS * CK) {
                int lb = tid / 3, k = tid - lb * 3;
                u32 i = ck * ROWS + (u32)lb;
                int valid = (i < lcnt);
                u16 e = valid ? wl[lst + i] : (u16)0;
                int b_ = valid ? (e >> 8) : 0;
                int t_ = valid ? (e & 0xFF) : 0;
                int raw = children[((size_t)b_ * CN + t_) * CK + k];
                int v = (raw < t_) && valid;
                msk[lb][k] = v ? 1.0f : 0.0f;
                cix[lb][k] = v ? raw : 0;
            }
            __syncthreads();

            // stage x: 32 rows x 64 float4; split hi/lo in-register
            for (int idx = tid; idx < ROWS * 64; idx += 1024) {
                int row = idx >> 6, c4 = idx & 63;
                float4v v = *(const float4v*)(emb + (size_t)nid[row] * CE + c4 * 4);
                ushort4v h4, l4;
                #pragma unroll
                for (int j = 0; j < 4; ++j) {
                    u16 hb = f2bfu(v[j]);
                    h4[j] = hb;
                    l4[j] = f2bfu(v[j] - bfu2f(hb));
                }
                *(ushort4v*)&Ahi[row][c4 * 4] = h4;
                *(ushort4v*)&Alo[row][c4 * 4] = l4;
            }
            // stage h: 96 (row,k) x 64 packed-16B chunks; split hi/lo while
            // staging (removes ALL unpack from the MFMA loop)
            for (int idx = tid; idx < ROWS * CK * 64; idx += 1024) {
                int r  = idx >> 6;             // 0..95
                int ch = idx & 63;             // 4-elem chunk
                int row = r / 3, k = r - row * 3;
                uint4v v = (uint4v){0u, 0u, 0u, 0u};
                if (msk[row][k] != 0.0f) {
                    const uint4v* src = (const uint4v*)(h_pk
                        + ((size_t)cix[row][k] * CB + brow[row]) * CH + 4 * ch);
                    v = *src;
                }
                ushort4v h4, l4;
                #pragma unroll
                for (int j = 0; j < 4; ++j) {
                    h4[j] = (u16)(v[j] >> 16);
                    l4[j] = (u16)(v[j] & 0xffffu);
                }
                int cc = CE + k * CH + 4 * ch;
                *(ushort4v*)&Ahi[row][cc] = h4;
                *(ushort4v*)&Alo[row][cc] = l4;
            }
            __syncthreads();

            // MFMA bf16x3: direct ds_read_b128 A-frags, 6 gate planes
            float4v accH[6], accL[6];
            #pragma unroll
            for (int q = 0; q < 6; ++q) {
                accH[q] = (float4v){0.f, 0.f, 0.f, 0.f};
                accL[q] = (float4v){0.f, 0.f, 0.f, 0.f};
            }
            #pragma unroll 4
            for (int ci = 0; ci < 32; ++ci) {
                short8v ahi = *(const short8v*)&Ahi[arow][ci * 32 + k8];
                short8v alo = *(const short8v*)&Alo[arow][ci * 32 + k8];
                #pragma unroll
                for (int q = 0; q < 6; ++q) {
                    short8v bh = *(const short8v*)(Whi + bb[q] + ci * 512);
                    short8v bl = *(const short8v*)(Wlo + bb[q] + ci * 512);
                    accH[q] = __builtin_amdgcn_mfma_f32_16x16x32_bf16(ahi, bh, accH[q], 0, 0, 0);
                    accL[q] = __builtin_amdgcn_mfma_f32_16x16x32_bf16(ahi, bl, accL[q], 0, 0, 0);
                    accL[q] = __builtin_amdgcn_mfma_f32_16x16x32_bf16(alo, bh, accL[q], 0, 0, 0);
                }
            }

            // fused cell phase, in-lane on D-layout (col=l&15, row=(l>>4)*4+r)
            #pragma unroll
            for (int r = 0; r < 4; ++r) {
                const int row = rg * 16 + (l >> 4) * 4 + r;
                if (rval[row]) {
                    const int b = brow[row], t_ = trow[row];
                    const float m0 = msk[row][0], m1 = msk[row][1], m2 = msk[row][2];
                    float g[6];
                    #pragma unroll
                    for (int q = 0; q < 6; ++q) {
                        int gc = q * CH + hcol;
                        g[q] = accH[q][r] + accL[q][r]
                             + Wx_b[gc] + m0 * Uh_b[gc] + m1 * Uh_b[CG_ + gc]
                                        + m2 * Uh_b[2 * CG_ + gc];
                    }
                    float ig = 1.0f / (1.0f + expf(-g[0]));
                    float og = 1.0f / (1.0f + expf(-g[1]));
                    float ug = tanhf(g[2]);
                    float c = ig * ug;
                    if (m0 != 0.0f) c += (1.0f / (1.0f + expf(-g[3]))) *
                        c_s[((size_t)cix[row][0] * CB + b) * CH + hcol];
                    if (m1 != 0.0f) c += (1.0f / (1.0f + expf(-g[4]))) *
                        c_s[((size_t)cix[row][1] * CB + b) * CH + hcol];
                    if (m2 != 0.0f) c += (1.0f / (1.0f + expf(-g[5]))) *
                        c_s[((size_t)cix[row][2] * CB + b) * CH + hcol];
                    float h = og * tanhf(c);
                    const size_t hx = ((size_t)t_ * CB + b) * CH + hcol;
                    u16 hb = f2bfu(h);
                    u32 hp = ((u32)hb << 16) | (u32)f2bfu(h - bfu2f(hb));
                    __hip_atomic_store(&h_pk[hx], hp, __ATOMIC_RELAXED, __HIP_MEMORY_SCOPE_AGENT);
                    __hip_atomic_store(&c_s[hx], c, __ATOMIC_RELAXED, __HIP_MEMORY_SCOPE_AGENT);
                    if (t_ == CN - 1) out[(size_t)b * CH + hcol] = h;
                }
            }
            __syncthreads();                   // LDS free before next chunk
        }

        if (L == NL - 1) break;

        // ---- light grid barrier per level (r12/r14-r20 verified) ----
        __syncthreads();
        if (tid == 0)
            __hip_atomic_store(&flags[bid * 16], L + 1,
                               __ATOMIC_RELAXED, __HIP_MEMORY_SCOPE_AGENT);
        for (;;) {
            int ok = 1;
            if (tid < 256)
                ok = (__hip_atomic_load(&flags[tid * 16], __ATOMIC_RELAXED,
                                        __HIP_MEMORY_SCOPE_AGENT) >= L + 1);
            if (__syncthreads_and(ok)) break;
            __builtin_amdgcn_s_sleep(2);
        }
    }
}

// ---------------------------------------------------------------------------
// Fallback: per-step kernel with fragment-ordered B (r17-r19-verified backup).
// ---------------------------------------------------------------------------
__global__ __launch_bounds__(768) void tree_step_mfma(
    const int* __restrict__ node_ids, const int* __restrict__ children,
    const float* __restrict__ emb,
    const u16* __restrict__ Whi, const u16* __restrict__ Wlo,
    const float* __restrict__ Wx_b, const float* __restrict__ Uh_b,
    u16* __restrict__ h_hi, u16* __restrict__ h_lo,
    float* __restrict__ c_s, float* __restrict__ out, const int t)
{
    const int tid = threadIdx.x;
    const int xcd  = blockIdx.x & 7;
    const int bidx = blockIdx.x >> 3;
    const int hi   = xcd * 2 + (bidx & 1);
    const int bi   = bidx >> 1;
    const int b0   = bi * 16;
    const int hh0  = hi * 16;

    __shared__ u16   Ahi[16][KTOT + 8];
    __shared__ u16   Alo[16][KTOT + 8];
    __shared__ float part[4][6][16][17];
    __shared__ int   nid[16];
    __shared__ float msk[16][3];
    __shared__ int   cix[16][3];

    const int wv    = tid >> 6;
    const int l     = tid & 63;
    const int np    = wv % 3;
    const int kq    = wv / 3;
    const int lan15 = l & 15;
    const int k8    = (l >> 4) * 8;

    if (tid < 16) nid[tid] = node_ids[(size_t)(b0 + tid) * CN + t];
    if (tid < 48) {
        int lb = tid / 3, k = tid - lb * 3;
        int raw = children[((size_t)(b0 + lb) * CN + t) * CK + k];
        int v = raw < t;
        msk[lb][k] = v ? 1.0f : 0.0f;
        cix[lb][k] = v ? raw : 0;
    }
    __syncthreads();

    for (int idx = tid; idx < 1024; idx += 768) {
        int lb = idx >> 6, c4 = idx & 63;
        float4v v = *(const float4v*)(emb + (size_t)nid[lb] * CE + c4 * 4);
        ushort4v h4, l4;
        #pragma unroll
        for (int j = 0; j < 4; ++j) {
            u16 hb = f2bfu(v[j]);
            h4[j] = hb;
            l4[j] = f2bfu(v[j] - bfu2f(hb));
        }
        *(ushort4v*)&Ahi[lb][c4 * 4] = h4;
        *(ushort4v*)&Alo[lb][c4 * 4] = l4;
    }
    for (int idx = tid; idx < 3072; idx += 768) {
        int r  = idx >> 6;
        int c  = idx & 63;
        int pl = c >> 5;
        int ch = c & 31;
        int lb = r / 3, k = r - lb * 3;
        uint4v val = (uint4v){0u, 0u, 0u, 0u};
        if (msk[lb][k] != 0.0f) {
            const u16* src = (pl ? h_lo : h_hi)
                + ((size_t)cix[lb][k] * CB + (b0 + lb)) * CH + ch * 8;
            val = *(const uint4v*)src;
        }
        u16* dst = (pl ? &Alo[lb][CE + k * CH + ch * 8]
                       : &Ahi[lb][CE + k * CH + ch * 8]);
        *(uint4v*)dst = val;
    }
    __syncthreads();

    {
        float4v acc[2][3];
        #pragma unroll
        for (int a = 0; a < 2; ++a)
            #pragma unroll
            for (int b2 = 0; b2 < 3; ++b2)
                acc[a][b2] = (float4v){0.f, 0.f, 0.f, 0.f};
        u32 fb0 = (u32)((np * 2 + 0) * 16 + hi) * 16384u + (u32)l * 8u;
        u32 fb1 = (u32)((np * 2 + 1) * 16 + hi) * 16384u + (u32)l * 8u;
        #pragma unroll
        for (int ci = 0; ci < 8; ++ci) {
            const int kb = (kq * 8 + ci) * 32 + k8;
            const u32 fo = (u32)(kq * 8 + ci) * 512u;
            short8v ahi = *(const short8v*)&Ahi[lan15][kb];
            short8v alo = *(const short8v*)&Alo[lan15][kb];
            short8v bh0 = *(const short8v*)(Whi + fb0 + fo);
            short8v bh1 = *(const short8v*)(Whi + fb1 + fo);
            short8v bl0 = *(const short8v*)(Wlo + fb0 + fo);
            short8v bl1 = *(const short8v*)(Wlo + fb1 + fo);
            acc[0][0] = __builtin_amdgcn_mfma_f32_16x16x32_bf16(ahi, bh0, acc[0][0], 0, 0, 0);
            acc[0][1] = __builtin_amdgcn_mfma_f32_16x16x32_bf16(ahi, bl0, acc[0][1], 0, 0, 0);
            acc[0][2] = __builtin_amdgcn_mfma_f32_16x16x32_bf16(alo, bh0, acc[0][2], 0, 0, 0);
            acc[1][0] = __builtin_amdgcn_mfma_f32_16x16x32_bf16(ahi, bh1, acc[1][0], 0, 0, 0);
            acc[1][1] = __builtin_amdgcn_mfma_f32_16x16x32_bf16(ahi, bl1, acc[1][1], 0, 0, 0);
            acc[1][2] = __builtin_amdgcn_mfma_f32_16x16x32_bf16(alo, bh1, acc[1][2], 0, 0, 0);
        }
        #pragma unroll
        for (int t2 = 0; t2 < 2; ++t2)
            #pragma unroll
            for (int r = 0; r < 4; ++r)
                part[kq][np * 2 + t2][(l >> 4) * 4 + r][lan15] =
                    acc[t2][0][r] + acc[t2][1][r] + acc[t2][2][r];
    }
    __syncthreads();

    if (tid < 256) {
        const int bb = tid >> 4, j2 = tid & 15;
        const int b = b0 + bb, hh = hh0 + j2;
        const float m0 = msk[bb][0], m1 = msk[bb][1], m2 = msk[bb][2];
        float g[6];
        #pragma unroll
        for (int q = 0; q < 6; ++q) {
            int gc = q * CH + hh;
            g[q] = part[0][q][bb][j2] + part[1][q][bb][j2]
                 + part[2][q][bb][j2] + part[3][q][bb][j2]
                 + Wx_b[gc] + m0 * Uh_b[gc] + m1 * Uh_b[CG_ + gc]
                            + m2 * Uh_b[2 * CG_ + gc];
        }
        float ig = 1.0f / (1.0f + expf(-g[0]));
        float og = 1.0f / (1.0f + expf(-g[1]));
        float ug = tanhf(g[2]);
        float c = ig * ug;
        if (m0 != 0.0f) c += (1.0f / (1.0f + expf(-g[3]))) * c_s[((size_t)cix[bb][0] * CB + b) * CH + hh];
        if (m1 != 0.0f) c += (1.0f / (1.0f + expf(-g[4]))) * c_s[((size_t)cix[bb][1] * CB + b) * CH + hh];
        if (m2 != 0.0f) c += (1.0f / (1.0f + expf(-g[5]))) * c_s[((size_t)cix[bb][2] * CB + b) * CH + hh];
        float h = og * tanhf(c);
        const size_t hx = ((size_t)t * CB + b) * CH + hh;
        u16 hb = f2bfu(h);
        h_hi[hx] = hb;
        h_lo[hx] = f2bfu(h - bfu2f(hb));
        c_s[hx] = c;
        if (t == CN - 1) out[(size_t)b * CH + hh] = h;
    }
}

__global__ void ws_report(float* out, int n, float val) {
    int i = blockIdx.x * blockDim.x + threadIdx.x;
    if (i < n) out[i] = val;
}

// ---------------------------------------------------------------------------
extern "C" void kernel_launch(void* const* d_in, const int* in_sizes, int n_in,
                              void* d_out, int out_size, void* d_ws, size_t ws_size,
                              hipStream_t stream) {
    float* outp = (float*)d_out;

    const int expect_sizes[7] = {65536, 196608, 8192000, 393216, 1536, 1179648, 4608};
    int bad = -1;
    if (n_in != 7) bad = 7;
    else for (int i = 0; i < 7; ++i) if (in_sizes[i] != expect_sizes[i]) { bad = i; break; }
    if (bad >= 0) {
        ws_report<<<(out_size + 255) / 256, 256, 0, stream>>>(outp, out_size, 1000.0f + bad);
        return;
    }

    const int*   node_ids = (const int*)d_in[0];
    const int*   children = (const int*)d_in[1];
    const float* emb      = (const float*)d_in[2];
    const float* Wx_w     = (const float*)d_in[3];
    const float* Wx_b     = (const float*)d_in[4];
    const float* Uh_w     = (const float*)d_in[5];
    const float* Uh_b     = (const float*)d_in[6];

    const size_t w_plane  = (size_t)CG_ * KTOT * 2;       //  3,145,728 B
    const size_t st_elems = (size_t)CN * CB * CH;         // 16,777,216
    const size_t flags_sz = 256 * 16 * sizeof(u32);       // 16 KB
    const size_t wl_sz    = (size_t)CB * CN * sizeof(u16);// 128 KB
    const size_t lvl_sz   = 256 * sizeof(u32);

    size_t off = 0;
    const size_t o_whi = off; off += w_plane;
    const size_t o_wlo = off; off += w_plane;
    const size_t o_hpk = off; off += st_elems * 4;
    const size_t o_cs  = off; off += st_elems * 4;
    const size_t o_flg = off; off += flags_sz;
    const size_t o_wl  = off; off += wl_sz;
    const size_t o_ls  = off; off += lvl_sz;
    const size_t o_lc  = off; off += lvl_sz;
    const size_t o_nl  = off; off += 64;
    const size_t need_lvl  = off;
    const size_t need_step = 2 * w_plane + st_elems * 2 * 2 + st_elems * 4;

    if (ws_size >= need_lvl) {
        char* w = (char*)d_ws;
        u16*   Whi = (u16*)(w + o_whi);
        u16*   Wlo = (u16*)(w + o_wlo);
        u32*   hpk = (u32*)(w + o_hpk);
        float* csb = (float*)(w + o_cs);
        u32*   flg = (u32*)(w + o_flg);
        u16*   wlp = (u16*)(w + o_wl);
        u32*   lsp = (u32*)(w + o_ls);
        u32*   lcp = (u32*)(w + o_lc);
        u32*   nlp = (u32*)(w + o_nl);

        prep_w<<<dim3(CG_), dim3(256), 0, stream>>>(Wx_w, Uh_w, Whi, Wlo);
        build_sched<<<dim3(1), dim3(256), 0, stream>>>(children, wlp, lsp, lcp, nlp);
        hipMemsetAsync(flg, 0, flags_sz, stream);

        void* args[] = { (void*)&node_ids, (void*)&children, (void*)&emb,
                         (void*)&Whi, (void*)&Wlo, (void*)&Wx_b, (void*)&Uh_b,
                         (void*)&hpk, (void*)&csb, (void*)&flg,
                         (void*)&wlp, (void*)&lsp, (void*)&lcp, (void*)&nlp,
                         (void*)&outp };
        hipError_t e = hipLaunchCooperativeKernel((const void*)tree_scan_lvl,
                                                  dim3(256), dim3(1024), args, 0, stream);
        if (e == hipSuccess) return;
    }
    if (ws_size >= need_step) {
        char* w = (char*)d_ws;
        u16*   Whi = (u16*)w;
        u16*   Wlo = (u16*)(w + w_plane);
        u16*   hhi = (u16*)(w + 2 * w_plane);
        u16*   hlo = (u16*)(w + 2 * w_plane + st_elems * 2);
        float* csb = (float*)(w + 2 * w_plane + 2 * st_elems * 2);

        prep_w<<<dim3(CG_), dim3(256), 0, stream>>>(Wx_w, Uh_w, Whi, Wlo);
        for (int t = 0; t < CN; ++t)
            tree_step_mfma<<<dim3(256), dim3(768), 0, stream>>>(
                node_ids, children, emb, Whi, Wlo, Wx_b, Uh_b,
                hhi, hlo, csb, outp, t);
    } else {
        ws_report<<<(out_size + 255) / 256, 256, 0, stream>>>(
            outp, out_size, (float)(ws_size >> 20));
    }
}

// Round 22
// 2100.085 us; speedup vs baseline: 1.2449x; 1.2449x over previous
//
#include <hip/hip_runtime.h>
#include <hip/hip_bf16.h>

#define CB 256      // batch
#define CN 256      // nodes
#define CK 3        // children per node
#define CE 256      // embedding dim
#define CH 256      // hidden dim
#define CG_ 1536    // gates = 6*CH
#define KTOT 1024   // E + K*H
#define ROWS 32     // rows per chunk (r19-verified geometry)
#define ASTR 1032   // A row stride in u16 (2064 B)

typedef __attribute__((ext_vector_type(8))) short short8v;          // 8 bf16
typedef __attribute__((ext_vector_type(4))) float float4v;          // MFMA C/D
typedef __attribute__((ext_vector_type(4))) unsigned int uint4v;
typedef __attribute__((ext_vector_type(4))) unsigned short ushort4v;
typedef unsigned int u32;
typedef unsigned long long u64;
typedef unsigned short u16;

__device__ __forceinline__ u16 f2bfu(float v) {
    __hip_bfloat16 h = __float2bfloat16(v);
    return __builtin_bit_cast(u16, h);
}
__device__ __forceinline__ float bfu2f(u16 u) {
    __hip_bfloat16 h = __builtin_bit_cast(__hip_bfloat16, u);
    return __bfloat162float(h);
}

// ---------------------------------------------------------------------------
// Prep (verified r17-r21): split W = [Wx_w ; Uh_w] into bf16 hi/lo planes in
// MFMA-FRAGMENT order [tile(16 gate cols)][ci][lane][8] — wave B-load = 1 KB
// contiguous.
// ---------------------------------------------------------------------------
__global__ __launch_bounds__(256) void prep_w(
    const float* __restrict__ Wx_w, const float* __restrict__ Uh_w,
    u16* __restrict__ Whi, u16* __restrict__ Wlo)
{
    const int g    = blockIdx.x;           // gate col 0..1535
    const int tile = g >> 4;
    const int gl   = g & 15;
    for (int k = threadIdx.x; k < KTOT; k += 256) {
        float w = (k < CE) ? Wx_w[(size_t)k * CG_ + g]
                           : Uh_w[(size_t)(k - CE) * CG_ + g];
        u16 hi = f2bfu(w);
        u16 lo = f2bfu(w - bfu2f(hi));
        int ci = k >> 5, kr = k & 31, lq = kr >> 3, j = kr & 7;
        size_t idx = ((size_t)(tile * 32 + ci) * 64 + lq * 16 + gl) * 8 + j;
        Whi[idx] = hi;
        Wlo[idx] = lo;
    }
}

// ---------------------------------------------------------------------------
// Level schedule build (verified r14-r21, incl. the 0xFFFF-collision fix).
// ---------------------------------------------------------------------------
__global__ __launch_bounds__(256) void build_sched(
    const int* __restrict__ children,
    u16* __restrict__ wl,             // [65536] (b<<8)|t
    u32* __restrict__ lvl_start,      // [256]
    u32* __restrict__ lvl_cnt,        // [256]
    u32* __restrict__ nlev)           // [1]
{
    __shared__ unsigned char lvl[CB][CN];   // 64 KB
    __shared__ u32 cnt[CN];
    __shared__ u32 pos[CN];
    const int b = threadIdx.x;

    for (int t = 0; t < CN; ++t) {
        int lv = 0;
        #pragma unroll
        for (int k = 0; k < CK; ++k) {
            int raw = children[((size_t)b * CN + t) * CK + k];
            if (raw < t) { int cl = (int)lvl[b][raw] + 1; if (cl > lv) lv = cl; }
        }
        lvl[b][t] = (unsigned char)lv;
    }
    cnt[b] = 0;
    __syncthreads();
    for (int t = 0; t < CN; ++t) atomicAdd(&cnt[lvl[b][t]], 1u);
    __syncthreads();
    if (b == 0) {
        u32 acc = 0, nl = 0;
        for (int L = 0; L < CN; ++L) {
            pos[L] = acc;
            if (cnt[L]) nl = (u32)L + 1;
            acc += cnt[L];
        }
        *nlev = nl;
    }
    __syncthreads();
    lvl_cnt[b]   = cnt[b];
    lvl_start[b] = pos[b];
    __syncthreads();
    for (int t = 0; t < CN; ++t) {
        int L = lvl[b][t];
        u32 p = atomicAdd(&pos[L], 1u);
        wl[p] = (u16)((b << 8) | t);
    }
}

// ---------------------------------------------------------------------------
// r22 scan = r19 wave mapping (8 waves = ctq, rg LOOPED IN-WAVE so B frags
// are loaded once per block — r21's rg-across-waves doubled B traffic and
// thrashed L2: FETCH 432MB->1.05GB) + r21's verified separate Ahi/Alo LDS
// staging (unpack once at stage time; MFMA loop is pure ds_read_b128 —
// removes ~1280 VALU ops/wave/chunk that dominated r19's VALUBusy).
// Everything else (ROWS=32, S=2, fragment-B, plain state loads, sc1 stores,
// flag barrier, schedule) byte-identical to r19 (best verified: 1870 us).
// ---------------------------------------------------------------------------
__global__ __launch_bounds__(512, 2) void tree_scan_lvl(
    const int* __restrict__ node_ids,          // [B][N]
    const int* __restrict__ children,          // [B][N][K]
    const float* __restrict__ emb,             // [V][E]
    const u16* __restrict__ Whi,               // fragment-ordered
    const u16* __restrict__ Wlo,               // fragment-ordered
    const float* __restrict__ Wx_b,            // [G]
    const float* __restrict__ Uh_b,            // [K][G]
    u32* __restrict__ h_pk,                    // [N][B][H] u32 (hi16|lo16)
    float* __restrict__ c_s,                   // [N][B][H] f32
    u32* __restrict__ flags,                   // [256*16], zeroed per call
    const u16* __restrict__ wl,                // [65536]
    const u32* __restrict__ lvl_start,         // [256]
    const u32* __restrict__ lvl_cnt,           // [256]
    const u32* __restrict__ nlev_p,            // [1]
    float* __restrict__ out)                   // [B][H] f32
{
    const int tid = threadIdx.x;
    const int bid = blockIdx.x;
    const int xcd   = bid & 7;
    const int slice = xcd >> 2;                          // 0..1 (4 XCDs each)
    const int sub   = ((bid >> 3) << 2) | (bid & 3);     // 0..127
    const int hh0   = slice * 128;

    __shared__ u16   Ahi[ROWS][ASTR];          // 66,048 B
    __shared__ u16   Alo[ROWS][ASTR];          // 66,048 B
    __shared__ int   nid[ROWS], brow[ROWS], trow[ROWS];
    __shared__ unsigned char rval[ROWS];
    __shared__ float msk[ROWS][3];
    __shared__ int   cix[ROWS][3];

    const int wv    = tid >> 6;                // 0..7 = col-tile (ctq)
    const int l     = tid & 63;
    const int lan15 = l & 15;
    const int k8    = (l >> 4) * 8;            // k-offset inside A row (u16)
    const int hcol  = hh0 + wv * 16 + lan15;   // this lane's h column

    // fragment-plane bases: tile = q*16 + slice*8 + ctq
    u32 bb[6];
    #pragma unroll
    for (int q = 0; q < 6; ++q)
        bb[q] = (u32)(q * 16 + slice * 8 + wv) * 16384u + (u32)l * 8u;

    const u32 NL = *nlev_p;

    for (u32 L = 0; L < NL; ++L) {
        const u32 lcnt   = lvl_cnt[L];
        const u32 lst    = lvl_start[L];
        const u32 nchunk = (lcnt + ROWS - 1) / ROWS;

        for (u32 ck = sub; ck < nchunk; ck += 128) {
            if (tid < ROWS) {
                u32 i = ck * ROWS + (u32)tid;
                int valid = (i < lcnt);
                u16 e = valid ? wl[lst + i] : (u16)0;
                rval[tid] = (unsigned char)valid;
                int b_ = valid ? (e >> 8) : 0;
                int t_ = valid ? (e & 0xFF) : 0;
                brow[tid] = b_;
                trow[tid] = t_;
                nid[tid]  = node_ids[(size_t)b_ * CN + t_];
            }
            if (tid < ROWS * CK) {
                int lb = tid / 3, k = tid - lb * 3;
                u32 i = ck * ROWS + (u32)lb;
                int valid = (i < lcnt);
                u16 e = valid ? wl[lst + i] : (u16)0;
                int b_ = valid ? (e >> 8) : 0;
                int t_ = valid ? (e & 0xFF) : 0;
                int raw = children[((size_t)b_ * CN + t_) * CK + k];
                int v = (raw < t_) && valid;
                msk[lb][k] = v ? 1.0f : 0.0f;
                cix[lb][k] = v ? raw : 0;
            }
            __syncthreads();

            // stage x: 32 rows x 64 float4; split hi/lo in-register
            for (int idx = tid; idx < ROWS * 64; idx += 512) {
                int row = idx >> 6, c4 = idx & 63;
                float4v v = *(const float4v*)(emb + (size_t)nid[row] * CE + c4 * 4);
                ushort4v h4, l4;
                #pragma unroll
                for (int j = 0; j < 4; ++j) {
                    u16 hb = f2bfu(v[j]);
                    h4[j] = hb;
                    l4[j] = f2bfu(v[j] - bfu2f(hb));
                }
                *(ushort4v*)&Ahi[row][c4 * 4] = h4;
                *(ushort4v*)&Alo[row][c4 * 4] = l4;
            }
            // stage h: 96 (row,k) x 64 packed-16B chunks; split hi/lo while
            // staging (no unpack left in the MFMA loop); plain cacheable loads
            for (int idx = tid; idx < ROWS * CK * 64; idx += 512) {
                int r  = idx >> 6;             // 0..95
                int ch = idx & 63;             // 4-elem chunk
                int row = r / 3, k = r - row * 3;
                uint4v v = (uint4v){0u, 0u, 0u, 0u};
                if (msk[row][k] != 0.0f) {
                    const uint4v* src = (const uint4v*)(h_pk
                        + ((size_t)cix[row][k] * CB + brow[row]) * CH + 4 * ch);
                    v = *src;
                }
                ushort4v h4, l4;
                #pragma unroll
                for (int j = 0; j < 4; ++j) {
                    h4[j] = (u16)(v[j] >> 16);
                    l4[j] = (u16)(v[j] & 0xffffu);
                }
                int cc = CE + k * CH + 4 * ch;
                *(ushort4v*)&Ahi[row][cc] = h4;
                *(ushort4v*)&Alo[row][cc] = l4;
            }
            __syncthreads();

            // MFMA bf16x3: direct ds_read_b128 A-frags; B loaded once per
            // (ci,q) and reused for BOTH row-groups (r18-verified pattern)
            float4v accH[2][6], accL[2][6];
            #pragma unroll
            for (int rg = 0; rg < 2; ++rg)
                #pragma unroll
                for (int q = 0; q < 6; ++q) {
                    accH[rg][q] = (float4v){0.f, 0.f, 0.f, 0.f};
                    accL[rg][q] = (float4v){0.f, 0.f, 0.f, 0.f};
                }
            #pragma unroll 2
            for (int ci = 0; ci < 32; ++ci) {
                short8v ahi0 = *(const short8v*)&Ahi[lan15][ci * 32 + k8];
                short8v alo0 = *(const short8v*)&Alo[lan15][ci * 32 + k8];
                short8v ahi1 = *(const short8v*)&Ahi[16 + lan15][ci * 32 + k8];
                short8v alo1 = *(const short8v*)&Alo[16 + lan15][ci * 32 + k8];
                #pragma unroll
                for (int q = 0; q < 6; ++q) {
                    short8v bh = *(const short8v*)(Whi + bb[q] + ci * 512);
                    short8v bl = *(const short8v*)(Wlo + bb[q] + ci * 512);
                    accH[0][q] = __builtin_amdgcn_mfma_f32_16x16x32_bf16(ahi0, bh, accH[0][q], 0, 0, 0);
                    accL[0][q] = __builtin_amdgcn_mfma_f32_16x16x32_bf16(ahi0, bl, accL[0][q], 0, 0, 0);
                    accL[0][q] = __builtin_amdgcn_mfma_f32_16x16x32_bf16(alo0, bh, accL[0][q], 0, 0, 0);
                    accH[1][q] = __builtin_amdgcn_mfma_f32_16x16x32_bf16(ahi1, bh, accH[1][q], 0, 0, 0);
                    accL[1][q] = __builtin_amdgcn_mfma_f32_16x16x32_bf16(ahi1, bl, accL[1][q], 0, 0, 0);
                    accL[1][q] = __builtin_amdgcn_mfma_f32_16x16x32_bf16(alo1, bh, accL[1][q], 0, 0, 0);
                }
            }

            // fused cell phase, in-lane on D-layout (col=l&15, row=(l>>4)*4+r)
            #pragma unroll
            for (int rg = 0; rg < 2; ++rg)
            #pragma unroll
            for (int r = 0; r < 4; ++r) {
                const int row = rg * 16 + (l >> 4) * 4 + r;
                if (rval[row]) {
                    const int b = brow[row], t_ = trow[row];
                    const float m0 = msk[row][0], m1 = msk[row][1], m2 = msk[row][2];
                    float g[6];
                    #pragma unroll
                    for (int q = 0; q < 6; ++q) {
                        int gc = q * CH + hcol;
                        g[q] = accH[rg][q][r] + accL[rg][q][r]
                             + Wx_b[gc] + m0 * Uh_b[gc] + m1 * Uh_b[CG_ + gc]
                                        + m2 * Uh_b[2 * CG_ + gc];
                    }
                    float ig = 1.0f / (1.0f + expf(-g[0]));
                    float og = 1.0f / (1.0f + expf(-g[1]));
                    float ug = tanhf(g[2]);
                    float c = ig * ug;
                    if (m0 != 0.0f) c += (1.0f / (1.0f + expf(-g[3]))) *
                        c_s[((size_t)cix[row][0] * CB + b) * CH + hcol];
                    if (m1 != 0.0f) c += (1.0f / (1.0f + expf(-g[4]))) *
                        c_s[((size_t)cix[row][1] * CB + b) * CH + hcol];
                    if (m2 != 0.0f) c += (1.0f / (1.0f + expf(-g[5]))) *
                        c_s[((size_t)cix[row][2] * CB + b) * CH + hcol];
                    float h = og * tanhf(c);
                    const size_t hx = ((size_t)t_ * CB + b) * CH + hcol;
                    u16 hb = f2bfu(h);
                    u32 hp = ((u32)hb << 16) | (u32)f2bfu(h - bfu2f(hb));
                    __hip_atomic_store(&h_pk[hx], hp, __ATOMIC_RELAXED, __HIP_MEMORY_SCOPE_AGENT);
                    __hip_atomic_store(&c_s[hx], c, __ATOMIC_RELAXED, __HIP_MEMORY_SCOPE_AGENT);
                    if (t_ == CN - 1) out[(size_t)b * CH + hcol] = h;
                }
            }
            __syncthreads();                   // LDS free before next chunk
        }

        if (L == NL - 1) break;

        // ---- light grid barrier per level (r12/r14-r21 verified) ----
        __syncthreads();
        if (tid == 0)
            __hip_atomic_store(&flags[bid * 16], L + 1,
                               __ATOMIC_RELAXED, __HIP_MEMORY_SCOPE_AGENT);
        for (;;) {
            int ok = 1;
            if (tid < 256)
                ok = (__hip_atomic_load(&flags[tid * 16], __ATOMIC_RELAXED,
                                        __HIP_MEMORY_SCOPE_AGENT) >= L + 1);
            if (__syncthreads_and(ok)) break;
            __builtin_amdgcn_s_sleep(2);
        }
    }
}

// ---------------------------------------------------------------------------
// Fallback: per-step kernel with fragment-ordered B (r17-r19-verified backup).
// ---------------------------------------------------------------------------
__global__ __launch_bounds__(768) void tree_step_mfma(
    const int* __restrict__ node_ids, const int* __restrict__ children,
    const float* __restrict__ emb,
    const u16* __restrict__ Whi, const u16* __restrict__ Wlo,
    const float* __restrict__ Wx_b, const float* __restrict__ Uh_b,
    u16* __restrict__ h_hi, u16* __restrict__ h_lo,
    float* __restrict__ c_s, float* __restrict__ out, const int t)
{
    const int tid = threadIdx.x;
    const int xcd  = blockIdx.x & 7;
    const int bidx = blockIdx.x >> 3;
    const int hi   = xcd * 2 + (bidx & 1);
    const int bi   = bidx >> 1;
    const int b0   = bi * 16;
    const int hh0  = hi * 16;

    __shared__ u16   Ahi[16][KTOT + 8];
    __shared__ u16   Alo[16][KTOT + 8];
    __shared__ float part[4][6][16][17];
    __shared__ int   nid[16];
    __shared__ float msk[16][3];
    __shared__ int   cix[16][3];

    const int wv    = tid >> 6;
    const int l     = tid & 63;
    const int np    = wv % 3;
    const int kq    = wv / 3;
    const int lan15 = l & 15;
    const int k8    = (l >> 4) * 8;

    if (tid < 16) nid[tid] = node_ids[(size_t)(b0 + tid) * CN + t];
    if (tid < 48) {
        int lb = tid / 3, k = tid - lb * 3;
        int raw = children[((size_t)(b0 + lb) * CN + t) * CK + k];
        int v = raw < t;
        msk[lb][k] = v ? 1.0f : 0.0f;
        cix[lb][k] = v ? raw : 0;
    }
    __syncthreads();

    for (int idx = tid; idx < 1024; idx += 768) {
        int lb = idx >> 6, c4 = idx & 63;
        float4v v = *(const float4v*)(emb + (size_t)nid[lb] * CE + c4 * 4);
        ushort4v h4, l4;
        #pragma unroll
        for (int j = 0; j < 4; ++j) {
            u16 hb = f2bfu(v[j]);
            h4[j] = hb;
            l4[j] = f2bfu(v[j] - bfu2f(hb));
        }
        *(ushort4v*)&Ahi[lb][c4 * 4] = h4;
        *(ushort4v*)&Alo[lb][c4 * 4] = l4;
    }
    for (int idx = tid; idx < 3072; idx += 768) {
        int r  = idx >> 6;
        int c  = idx & 63;
        int pl = c >> 5;
        int ch = c & 31;
        int lb = r / 3, k = r - lb * 3;
        uint4v val = (uint4v){0u, 0u, 0u, 0u};
        if (msk[lb][k] != 0.0f) {
            const u16* src = (pl ? h_lo : h_hi)
                + ((size_t)cix[lb][k] * CB + (b0 + lb)) * CH + ch * 8;
            val = *(const uint4v*)src;
        }
        u16* dst = (pl ? &Alo[lb][CE + k * CH + ch * 8]
                       : &Ahi[lb][CE + k * CH + ch * 8]);
        *(uint4v*)dst = val;
    }
    __syncthreads();

    {
        float4v acc[2][3];
        #pragma unroll
        for (int a = 0; a < 2; ++a)
            #pragma unroll
            for (int b2 = 0; b2 < 3; ++b2)
                acc[a][b2] = (float4v){0.f, 0.f, 0.f, 0.f};
        u32 fb0 = (u32)((np * 2 + 0) * 16 + hi) * 16384u + (u32)l * 8u;
        u32 fb1 = (u32)((np * 2 + 1) * 16 + hi) * 16384u + (u32)l * 8u;
        #pragma unroll
        for (int ci = 0; ci < 8; ++ci) {
            const int kb = (kq * 8 + ci) * 32 + k8;
            const u32 fo = (u32)(kq * 8 + ci) * 512u;
            short8v ahi = *(const short8v*)&Ahi[lan15][kb];
            short8v alo = *(const short8v*)&Alo[lan15][kb];
            short8v bh0 = *(const short8v*)(Whi + fb0 + fo);
            short8v bh1 = *(const short8v*)(Whi + fb1 + fo);
            short8v bl0 = *(const short8v*)(Wlo + fb0 + fo);
            short8v bl1 = *(const short8v*)(Wlo + fb1 + fo);
            acc[0][0] = __builtin_amdgcn_mfma_f32_16x16x32_bf16(ahi, bh0, acc[0][0], 0, 0, 0);
            acc[0][1] = __builtin_amdgcn_mfma_f32_16x16x32_bf16(ahi, bl0, acc[0][1], 0, 0, 0);
            acc[0][2] = __builtin_amdgcn_mfma_f32_16x16x32_bf16(alo, bh0, acc[0][2], 0, 0, 0);
            acc[1][0] = __builtin_amdgcn_mfma_f32_16x16x32_bf16(ahi, bh1, acc[1][0], 0, 0, 0);
            acc[1][1] = __builtin_amdgcn_mfma_f32_16x16x32_bf16(ahi, bl1, acc[1][1], 0, 0, 0);
            acc[1][2] = __builtin_amdgcn_mfma_f32_16x16x32_bf16(alo, bh1, acc[1][2], 0, 0, 0);
        }
        #pragma unroll
        for (int t2 = 0; t2 < 2; ++t2)
            #pragma unroll
            for (int r = 0; r < 4; ++r)
                part[kq][np * 2 + t2][(l >> 4) * 4 + r][lan15] =
                    acc[t2][0][r] + acc[t2][1][r] + acc[t2][2][r];
    }
    __syncthreads();

    if (tid < 256) {
        const int bb = tid >> 4, j2 = tid & 15;
        const int b = b0 + bb, hh = hh0 + j2;
        const float m0 = msk[bb][0], m1 = msk[bb][1], m2 = msk[bb][2];
        float g[6];
        #pragma unroll
        for (int q = 0; q < 6; ++q) {
            int gc = q * CH + hh;
            g[q] = part[0][q][bb][j2] + part[1][q][bb][j2]
                 + part[2][q][bb][j2] + part[3][q][bb][j2]
                 + Wx_b[gc] + m0 * Uh_b[gc] + m1 * Uh_b[CG_ + gc]
                            + m2 * Uh_b[2 * CG_ + gc];
        }
        float ig = 1.0f / (1.0f + expf(-g[0]));
        float og = 1.0f / (1.0f + expf(-g[1]));
        float ug = tanhf(g[2]);
        float c = ig * ug;
        if (m0 != 0.0f) c += (1.0f / (1.0f + expf(-g[3]))) * c_s[((size_t)cix[bb][0] * CB + b) * CH + hh];
        if (m1 != 0.0f) c += (1.0f / (1.0f + expf(-g[4]))) * c_s[((size_t)cix[bb][1] * CB + b) * CH + hh];
        if (m2 != 0.0f) c += (1.0f / (1.0f + expf(-g[5]))) * c_s[((size_t)cix[bb][2] * CB + b) * CH + hh];
        float h = og * tanhf(c);
        const size_t hx = ((size_t)t * CB + b) * CH + hh;
        u16 hb = f2bfu(h);
        h_hi[hx] = hb;
        h_lo[hx] = f2bfu(h - bfu2f(hb));
        c_s[hx] = c;
        if (t == CN - 1) out[(size_t)b * CH + hh] = h;
    }
}

__global__ void ws_report(float* out, int n, float val) {
    int i = blockIdx.x * blockDim.x + threadIdx.x;
    if (i < n) out[i] = val;
}

// ---------------------------------------------------------------------------
extern "C" void kernel_launch(void* const* d_in, const int* in_sizes, int n_in,
                              void* d_out, int out_size, void* d_ws, size_t ws_size,
                              hipStream_t stream) {
    float* outp = (float*)d_out;

    const int expect_sizes[7] = {65536, 196608, 8192000, 393216, 1536, 1179648, 4608};
    int bad = -1;
    if (n_in != 7) bad = 7;
    else for (int i = 0; i < 7; ++i) if (in_sizes[i] != expect_sizes[i]) { bad = i; break; }
    if (bad >= 0) {
        ws_report<<<(out_size + 255) / 256, 256, 0, stream>>>(outp, out_size, 1000.0f + bad);
        return;
    }

    const int*   node_ids = (const int*)d_in[0];
    const int*   children = (const int*)d_in[1];
    const float* emb      = (const float*)d_in[2];
    const float* Wx_w     = (const float*)d_in[3];
    const float* Wx_b     = (const float*)d_in[4];
    const float* Uh_w     = (const float*)d_in[5];
    const float* Uh_b     = (const float*)d_in[6];

    const size_t w_plane  = (size_t)CG_ * KTOT * 2;       //  3,145,728 B
    const size_t st_elems = (size_t)CN * CB * CH;         // 16,777,216
    const size_t flags_sz = 256 * 16 * sizeof(u32);       // 16 KB
    const size_t wl_sz    = (size_t)CB * CN * sizeof(u16);// 128 KB
    const size_t lvl_sz   = 256 * sizeof(u32);

    size_t off = 0;
    const size_t o_whi = off; off += w_plane;
    const size_t o_wlo = off; off += w_plane;
    const size_t o_hpk = off; off += st_elems * 4;
    const size_t o_cs  = off; off += st_elems * 4;
    const size_t o_flg = off; off += flags_sz;
    const size_t o_wl  = off; off += wl_sz;
    const size_t o_ls  = off; off += lvl_sz;
    const size_t o_lc  = off; off += lvl_sz;
    const size_t o_nl  = off; off += 64;
    const size_t need_lvl  = off;
    const size_t need_step = 2 * w_plane + st_elems * 2 * 2 + st_elems * 4;

    if (ws_size >= need_lvl) {
        char* w = (char*)d_ws;
        u16*   Whi = (u16*)(w + o_whi);
        u16*   Wlo = (u16*)(w + o_wlo);
        u32*   hpk = (u32*)(w + o_hpk);
        float* csb = (float*)(w + o_cs);
        u32*   flg = (u32*)(w + o_flg);
        u16*   wlp = (u16*)(w + o_wl);
        u32*   lsp = (u32*)(w + o_ls);
        u32*   lcp = (u32*)(w + o_lc);
        u32*   nlp = (u32*)(w + o_nl);

        prep_w<<<dim3(CG_), dim3(256), 0, stream>>>(Wx_w, Uh_w, Whi, Wlo);
        build_sched<<<dim3(1), dim3(256), 0, stream>>>(children, wlp, lsp, lcp, nlp);
        hipMemsetAsync(flg, 0, flags_sz, stream);

        void* args[] = { (void*)&node_ids, (void*)&children, (void*)&emb,
                         (void*)&Whi, (void*)&Wlo, (void*)&Wx_b, (void*)&Uh_b,
                         (void*)&hpk, (void*)&csb, (void*)&flg,
                         (void*)&wlp, (void*)&lsp, (void*)&lcp, (void*)&nlp,
                         (void*)&outp };
        hipError_t e = hipLaunchCooperativeKernel((const void*)tree_scan_lvl,
                                                  dim3(256), dim3(512), args, 0, stream);
        if (e == hipSuccess) return;
    }
    if (ws_size >= need_step) {
        char* w = (char*)d_ws;
        u16*   Whi = (u16*)w;
        u16*   Wlo = (u16*)(w + w_plane);
        u16*   hhi = (u16*)(w + 2 * w_plane);
        u16*   hlo = (u16*)(w + 2 * w_plane + st_elems * 2);
        float* csb = (float*)(w + 2 * w_plane + 2 * st_elems * 2);

        prep_w<<<dim3(CG_), dim3(256), 0, stream>>>(Wx_w, Uh_w, Whi, Wlo);
        for (int t = 0; t < CN; ++t)
            tree_step_mfma<<<dim3(256), dim3(768), 0, stream>>>(
                node_ids, children, emb, Whi, Wlo, Wx_b, Uh_b,
                hhi, hlo, csb, outp, t);
    } else {
        ws_report<<<(out_size + 255) / 256, 256, 0, stream>>>(
            outp, out_size, (float)(ws_size >> 20));
    }
}

// Round 23
// 1932.964 us; speedup vs baseline: 1.3525x; 1.0865x over previous
//
#include <hip/hip_runtime.h>
#include <hip/hip_bf16.h>

#define CB 256      // batch
#define CN 256      // nodes
#define CK 3        // children per node
#define CE 256      // embedding dim
#define CH 256      // hidden dim
#define CG_ 1536    // gates = 6*CH
#define KTOT 1024   // E + K*H
#define ROWS 32     // rows per chunk (r19/r22-verified geometry)
#define ASTR 1032   // A row stride in u16 (2064 B)

typedef __attribute__((ext_vector_type(8))) short short8v;          // 8 bf16
typedef __attribute__((ext_vector_type(4))) float float4v;          // MFMA C/D
typedef __attribute__((ext_vector_type(4))) unsigned int uint4v;
typedef __attribute__((ext_vector_type(4))) unsigned short ushort4v;
typedef unsigned int u32;
typedef unsigned long long u64;
typedef unsigned short u16;

__device__ __forceinline__ u16 f2bfu(float v) {
    __hip_bfloat16 h = __float2bfloat16(v);
    return __builtin_bit_cast(u16, h);
}
__device__ __forceinline__ float bfu2f(u16 u) {
    __hip_bfloat16 h = __builtin_bit_cast(__hip_bfloat16, u);
    return __bfloat162float(h);
}

// ---------------------------------------------------------------------------
// Prep (verified r17-r22): split W = [Wx_w ; Uh_w] into bf16 hi/lo planes in
// MFMA-FRAGMENT order [tile(16 gate cols)][ci][lane][8] — wave B-load = 1 KB
// contiguous.
// ---------------------------------------------------------------------------
__global__ __launch_bounds__(256) void prep_w(
    const float* __restrict__ Wx_w, const float* __restrict__ Uh_w,
    u16* __restrict__ Whi, u16* __restrict__ Wlo)
{
    const int g    = blockIdx.x;           // gate col 0..1535
    const int tile = g >> 4;
    const int gl   = g & 15;
    for (int k = threadIdx.x; k < KTOT; k += 256) {
        float w = (k < CE) ? Wx_w[(size_t)k * CG_ + g]
                           : Uh_w[(size_t)(k - CE) * CG_ + g];
        u16 hi = f2bfu(w);
        u16 lo = f2bfu(w - bfu2f(hi));
        int ci = k >> 5, kr = k & 31, lq = kr >> 3, j = kr & 7;
        size_t idx = ((size_t)(tile * 32 + ci) * 64 + lq * 16 + gl) * 8 + j;
        Whi[idx] = hi;
        Wlo[idx] = lo;
    }
}

// ---------------------------------------------------------------------------
// Level schedule build (verified r14-r22, incl. the 0xFFFF-collision fix).
// ---------------------------------------------------------------------------
__global__ __launch_bounds__(256) void build_sched(
    const int* __restrict__ children,
    u16* __restrict__ wl,             // [65536] (b<<8)|t
    u32* __restrict__ lvl_start,      // [256]
    u32* __restrict__ lvl_cnt,        // [256]
    u32* __restrict__ nlev)           // [1]
{
    __shared__ unsigned char lvl[CB][CN];   // 64 KB
    __shared__ u32 cnt[CN];
    __shared__ u32 pos[CN];
    const int b = threadIdx.x;

    for (int t = 0; t < CN; ++t) {
        int lv = 0;
        #pragma unroll
        for (int k = 0; k < CK; ++k) {
            int raw = children[((size_t)b * CN + t) * CK + k];
            if (raw < t) { int cl = (int)lvl[b][raw] + 1; if (cl > lv) lv = cl; }
        }
        lvl[b][t] = (unsigned char)lv;
    }
    cnt[b] = 0;
    __syncthreads();
    for (int t = 0; t < CN; ++t) atomicAdd(&cnt[lvl[b][t]], 1u);
    __syncthreads();
    if (b == 0) {
        u32 acc = 0, nl = 0;
        for (int L = 0; L < CN; ++L) {
            pos[L] = acc;
            if (cnt[L]) nl = (u32)L + 1;
            acc += cnt[L];
        }
        *nlev = nl;
    }
    __syncthreads();
    lvl_cnt[b]   = cnt[b];
    lvl_start[b] = pos[b];
    __syncthreads();
    for (int t = 0; t < CN; ++t) {
        int L = lvl[b][t];
        u32 p = atomicAdd(&pos[L], 1u);
        wl[p] = (u16)((b << 8) | t);
    }
}

// ---------------------------------------------------------------------------
// r23 scan = r22 (best verified class: 1931 us steady) + two latency hoists:
//  1. bias registers (Wx_b / 3x Uh_b per gate, hcol-only dependent) loaded
//     ONCE before the level loop — removes 24 latency-exposed loads from
//     every chunk's serial cell phase.
//  2. c_s child prefetch: children's c values are stable within a level, so
//     all 24 per-thread c-loads are issued right after staging and hidden
//     under the MFMA loop; cell reads registers.
// Pure load motion: values and summation order identical to r22.
// ---------------------------------------------------------------------------
__global__ __launch_bounds__(512, 2) void tree_scan_lvl(
    const int* __restrict__ node_ids,          // [B][N]
    const int* __restrict__ children,          // [B][N][K]
    const float* __restrict__ emb,             // [V][E]
    const u16* __restrict__ Whi,               // fragment-ordered
    const u16* __restrict__ Wlo,               // fragment-ordered
    const float* __restrict__ Wx_b,            // [G]
    const float* __restrict__ Uh_b,            // [K][G]
    u32* __restrict__ h_pk,                    // [N][B][H] u32 (hi16|lo16)
    float* __restrict__ c_s,                   // [N][B][H] f32
    u32* __restrict__ flags,                   // [256*16], zeroed per call
    const u16* __restrict__ wl,                // [65536]
    const u32* __restrict__ lvl_start,         // [256]
    const u32* __restrict__ lvl_cnt,           // [256]
    const u32* __restrict__ nlev_p,            // [1]
    float* __restrict__ out)                   // [B][H] f32
{
    const int tid = threadIdx.x;
    const int bid = blockIdx.x;
    const int xcd   = bid & 7;
    const int slice = xcd >> 2;                          // 0..1 (4 XCDs each)
    const int sub   = ((bid >> 3) << 2) | (bid & 3);     // 0..127
    const int hh0   = slice * 128;

    __shared__ u16   Ahi[ROWS][ASTR];          // 66,048 B
    __shared__ u16   Alo[ROWS][ASTR];          // 66,048 B
    __shared__ int   nid[ROWS], brow[ROWS], trow[ROWS];
    __shared__ unsigned char rval[ROWS];
    __shared__ float msk[ROWS][3];
    __shared__ int   cix[ROWS][3];

    const int wv    = tid >> 6;                // 0..7 = col-tile (ctq)
    const int l     = tid & 63;
    const int lan15 = l & 15;
    const int k8    = (l >> 4) * 8;            // k-offset inside A row (u16)
    const int hcol  = hh0 + wv * 16 + lan15;   // this lane's h column

    // fragment-plane bases: tile = q*16 + slice*8 + ctq
    u32 bb[6];
    #pragma unroll
    for (int q = 0; q < 6; ++q)
        bb[q] = (u32)(q * 16 + slice * 8 + wv) * 16384u + (u32)l * 8u;

    // ---- hoist 1: bias registers (hcol-dependent only; loaded once) ----
    float bwx[6], bu0[6], bu1[6], bu2[6];
    #pragma unroll
    for (int q = 0; q < 6; ++q) {
        int gc = q * CH + hcol;
        bwx[q] = Wx_b[gc];
        bu0[q] = Uh_b[gc];
        bu1[q] = Uh_b[CG_ + gc];
        bu2[q] = Uh_b[2 * CG_ + gc];
    }

    const u32 NL = *nlev_p;

    for (u32 L = 0; L < NL; ++L) {
        const u32 lcnt   = lvl_cnt[L];
        const u32 lst    = lvl_start[L];
        const u32 nchunk = (lcnt + ROWS - 1) / ROWS;

        for (u32 ck = sub; ck < nchunk; ck += 128) {
            if (tid < ROWS) {
                u32 i = ck * ROWS + (u32)tid;
                int valid = (i < lcnt);
                u16 e = valid ? wl[lst + i] : (u16)0;
                rval[tid] = (unsigned char)valid;
                int b_ = valid ? (e >> 8) : 0;
                int t_ = valid ? (e & 0xFF) : 0;
                brow[tid] = b_;
                trow[tid] = t_;
                nid[tid]  = node_ids[(size_t)b_ * CN + t_];
            }
            if (tid < ROWS * CK) {
                int lb = tid / 3, k = tid - lb * 3;
                u32 i = ck * ROWS + (u32)lb;
                int valid = (i < lcnt);
                u16 e = valid ? wl[lst + i] : (u16)0;
                int b_ = valid ? (e >> 8) : 0;
                int t_ = valid ? (e & 0xFF) : 0;
                int raw = children[((size_t)b_ * CN + t_) * CK + k];
                int v = (raw < t_) && valid;
                msk[lb][k] = v ? 1.0f : 0.0f;
                cix[lb][k] = v ? raw : 0;
            }
            __syncthreads();

            // stage x: 32 rows x 64 float4; split hi/lo in-register
            for (int idx = tid; idx < ROWS * 64; idx += 512) {
                int row = idx >> 6, c4 = idx & 63;
                float4v v = *(const float4v*)(emb + (size_t)nid[row] * CE + c4 * 4);
                ushort4v h4, l4;
                #pragma unroll
                for (int j = 0; j < 4; ++j) {
                    u16 hb = f2bfu(v[j]);
                    h4[j] = hb;
                    l4[j] = f2bfu(v[j] - bfu2f(hb));
                }
                *(ushort4v*)&Ahi[row][c4 * 4] = h4;
                *(ushort4v*)&Alo[row][c4 * 4] = l4;
            }
            // stage h: 96 (row,k) x 64 packed-16B chunks; split hi/lo while
            // staging; plain cacheable loads (r19-verified)
            for (int idx = tid; idx < ROWS * CK * 64; idx += 512) {
                int r  = idx >> 6;             // 0..95
                int ch = idx & 63;             // 4-elem chunk
                int row = r / 3, k = r - row * 3;
                uint4v v = (uint4v){0u, 0u, 0u, 0u};
                if (msk[row][k] != 0.0f) {
                    const uint4v* src = (const uint4v*)(h_pk
                        + ((size_t)cix[row][k] * CB + brow[row]) * CH + 4 * ch);
                    v = *src;
                }
                ushort4v h4, l4;
                #pragma unroll
                for (int j = 0; j < 4; ++j) {
                    h4[j] = (u16)(v[j] >> 16);
                    l4[j] = (u16)(v[j] & 0xffffu);
                }
                int cc = CE + k * CH + 4 * ch;
                *(ushort4v*)&Ahi[row][cc] = h4;
                *(ushort4v*)&Alo[row][cc] = l4;
            }
            __syncthreads();

            // ---- hoist 2: c_s child prefetch (stable within the level;
            // issued before MFMA so the matrix loop hides the latency) ----
            float cpre[2][4][3];
            #pragma unroll
            for (int rg = 0; rg < 2; ++rg)
                #pragma unroll
                for (int r = 0; r < 4; ++r) {
                    const int row = rg * 16 + (l >> 4) * 4 + r;
                    const int b = brow[row];
                    #pragma unroll
                    for (int k = 0; k < 3; ++k)
                        cpre[rg][r][k] =
                            c_s[((size_t)cix[row][k] * CB + b) * CH + hcol];
                }

            // MFMA bf16x3: direct ds_read_b128 A-frags; B loaded once per
            // (ci,q) and reused for BOTH row-groups (r18/r22 pattern)
            float4v accH[2][6], accL[2][6];
            #pragma unroll
            for (int rg = 0; rg < 2; ++rg)
                #pragma unroll
                for (int q = 0; q < 6; ++q) {
                    accH[rg][q] = (float4v){0.f, 0.f, 0.f, 0.f};
                    accL[rg][q] = (float4v){0.f, 0.f, 0.f, 0.f};
                }
            #pragma unroll 2
            for (int ci = 0; ci < 32; ++ci) {
                short8v ahi0 = *(const short8v*)&Ahi[lan15][ci * 32 + k8];
                short8v alo0 = *(const short8v*)&Alo[lan15][ci * 32 + k8];
                short8v ahi1 = *(const short8v*)&Ahi[16 + lan15][ci * 32 + k8];
                short8v alo1 = *(const short8v*)&Alo[16 + lan15][ci * 32 + k8];
                #pragma unroll
                for (int q = 0; q < 6; ++q) {
                    short8v bh = *(const short8v*)(Whi + bb[q] + ci * 512);
                    short8v bl = *(const short8v*)(Wlo + bb[q] + ci * 512);
                    accH[0][q] = __builtin_amdgcn_mfma_f32_16x16x32_bf16(ahi0, bh, accH[0][q], 0, 0, 0);
                    accL[0][q] = __builtin_amdgcn_mfma_f32_16x16x32_bf16(ahi0, bl, accL[0][q], 0, 0, 0);
                    accL[0][q] = __builtin_amdgcn_mfma_f32_16x16x32_bf16(alo0, bh, accL[0][q], 0, 0, 0);
                    accH[1][q] = __builtin_amdgcn_mfma_f32_16x16x32_bf16(ahi1, bh, accH[1][q], 0, 0, 0);
                    accL[1][q] = __builtin_amdgcn_mfma_f32_16x16x32_bf16(ahi1, bl, accL[1][q], 0, 0, 0);
                    accL[1][q] = __builtin_amdgcn_mfma_f32_16x16x32_bf16(alo1, bh, accL[1][q], 0, 0, 0);
                }
            }

            // fused cell phase, in-lane on D-layout (col=l&15, row=(l>>4)*4+r)
            #pragma unroll
            for (int rg = 0; rg < 2; ++rg)
            #pragma unroll
            for (int r = 0; r < 4; ++r) {
                const int row = rg * 16 + (l >> 4) * 4 + r;
                if (rval[row]) {
                    const int b = brow[row], t_ = trow[row];
                    const float m0 = msk[row][0], m1 = msk[row][1], m2 = msk[row][2];
                    float g[6];
                    #pragma unroll
                    for (int q = 0; q < 6; ++q)
                        g[q] = accH[rg][q][r] + accL[rg][q][r]
                             + bwx[q] + m0 * bu0[q] + m1 * bu1[q] + m2 * bu2[q];
                    float ig = 1.0f / (1.0f + expf(-g[0]));
                    float og = 1.0f / (1.0f + expf(-g[1]));
                    float ug = tanhf(g[2]);
                    float c = ig * ug;
                    if (m0 != 0.0f) c += (1.0f / (1.0f + expf(-g[3]))) * cpre[rg][r][0];
                    if (m1 != 0.0f) c += (1.0f / (1.0f + expf(-g[4]))) * cpre[rg][r][1];
                    if (m2 != 0.0f) c += (1.0f / (1.0f + expf(-g[5]))) * cpre[rg][r][2];
                    float h = og * tanhf(c);
                    const size_t hx = ((size_t)t_ * CB + b) * CH + hcol;
                    u16 hb = f2bfu(h);
                    u32 hp = ((u32)hb << 16) | (u32)f2bfu(h - bfu2f(hb));
                    __hip_atomic_store(&h_pk[hx], hp, __ATOMIC_RELAXED, __HIP_MEMORY_SCOPE_AGENT);
                    __hip_atomic_store(&c_s[hx], c, __ATOMIC_RELAXED, __HIP_MEMORY_SCOPE_AGENT);
                    if (t_ == CN - 1) out[(size_t)b * CH + hcol] = h;
                }
            }
            __syncthreads();                   // LDS free before next chunk
        }

        if (L == NL - 1) break;

        // ---- light grid barrier per level (r12/r14-r22 verified) ----
        __syncthreads();
        if (tid == 0)
            __hip_atomic_store(&flags[bid * 16], L + 1,
                               __ATOMIC_RELAXED, __HIP_MEMORY_SCOPE_AGENT);
        for (;;) {
            int ok = 1;
            if (tid < 256)
                ok = (__hip_atomic_load(&flags[tid * 16], __ATOMIC_RELAXED,
                                        __HIP_MEMORY_SCOPE_AGENT) >= L + 1);
            if (__syncthreads_and(ok)) break;
            __builtin_amdgcn_s_sleep(2);
        }
    }
}

// ---------------------------------------------------------------------------
// Fallback: per-step kernel with fragment-ordered B (r17-r22-verified backup).
// ---------------------------------------------------------------------------
__global__ __launch_bounds__(768) void tree_step_mfma(
    const int* __restrict__ node_ids, const int* __restrict__ children,
    const float* __restrict__ emb,
    const u16* __restrict__ Whi, const u16* __restrict__ Wlo,
    const float* __restrict__ Wx_b, const float* __restrict__ Uh_b,
    u16* __restrict__ h_hi, u16* __restrict__ h_lo,
    float* __restrict__ c_s, float* __restrict__ out, const int t)
{
    const int tid = threadIdx.x;
    const int xcd  = blockIdx.x & 7;
    const int bidx = blockIdx.x >> 3;
    const int hi   = xcd * 2 + (bidx & 1);
    const int bi   = bidx >> 1;
    const int b0   = bi * 16;
    const int hh0  = hi * 16;

    __shared__ u16   Ahi[16][KTOT + 8];
    __shared__ u16   Alo[16][KTOT + 8];
    __shared__ float part[4][6][16][17];
    __shared__ int   nid[16];
    __shared__ float msk[16][3];
    __shared__ int   cix[16][3];

    const int wv    = tid >> 6;
    const int l     = tid & 63;
    const int np    = wv % 3;
    const int kq    = wv / 3;
    const int lan15 = l & 15;
    const int k8    = (l >> 4) * 8;

    if (tid < 16) nid[tid] = node_ids[(size_t)(b0 + tid) * CN + t];
    if (tid < 48) {
        int lb = tid / 3, k = tid - lb * 3;
        int raw = children[((size_t)(b0 + lb) * CN + t) * CK + k];
        int v = raw < t;
        msk[lb][k] = v ? 1.0f : 0.0f;
        cix[lb][k] = v ? raw : 0;
    }
    __syncthreads();

    for (int idx = tid; idx < 1024; idx += 768) {
        int lb = idx >> 6, c4 = idx & 63;
        float4v v = *(const float4v*)(emb + (size_t)nid[lb] * CE + c4 * 4);
        ushort4v h4, l4;
        #pragma unroll
        for (int j = 0; j < 4; ++j) {
            u16 hb = f2bfu(v[j]);
            h4[j] = hb;
            l4[j] = f2bfu(v[j] - bfu2f(hb));
        }
        *(ushort4v*)&Ahi[lb][c4 * 4] = h4;
        *(ushort4v*)&Alo[lb][c4 * 4] = l4;
    }
    for (int idx = tid; idx < 3072; idx += 768) {
        int r  = idx >> 6;
        int c  = idx & 63;
        int pl = c >> 5;
        int ch = c & 31;
        int lb = r / 3, k = r - lb * 3;
        uint4v val = (uint4v){0u, 0u, 0u, 0u};
        if (msk[lb][k] != 0.0f) {
            const u16* src = (pl ? h_lo : h_hi)
                + ((size_t)cix[lb][k] * CB + (b0 + lb)) * CH + ch * 8;
            val = *(const uint4v*)src;
        }
        u16* dst = (pl ? &Alo[lb][CE + k * CH + ch * 8]
                       : &Ahi[lb][CE + k * CH + ch * 8]);
        *(uint4v*)dst = val;
    }
    __syncthreads();

    {
        float4v acc[2][3];
        #pragma unroll
        for (int a = 0; a < 2; ++a)
            #pragma unroll
            for (int b2 = 0; b2 < 3; ++b2)
                acc[a][b2] = (float4v){0.f, 0.f, 0.f, 0.f};
        u32 fb0 = (u32)((np * 2 + 0) * 16 + hi) * 16384u + (u32)l * 8u;
        u32 fb1 = (u32)((np * 2 + 1) * 16 + hi) * 16384u + (u32)l * 8u;
        #pragma unroll
        for (int ci = 0; ci < 8; ++ci) {
            const int kb = (kq * 8 + ci) * 32 + k8;
            const u32 fo = (u32)(kq * 8 + ci) * 512u;
            short8v ahi = *(const short8v*)&Ahi[lan15][kb];
            short8v alo = *(const short8v*)&Alo[lan15][kb];
            short8v bh0 = *(const short8v*)(Whi + fb0 + fo);
            short8v bh1 = *(const short8v*)(Whi + fb1 + fo);
            short8v bl0 = *(const short8v*)(Wlo + fb0 + fo);
            short8v bl1 = *(const short8v*)(Wlo + fb1 + fo);
            acc[0][0] = __builtin_amdgcn_mfma_f32_16x16x32_bf16(ahi, bh0, acc[0][0], 0, 0, 0);
            acc[0][1] = __builtin_amdgcn_mfma_f32_16x16x32_bf16(ahi, bl0, acc[0][1], 0, 0, 0);
            acc[0][2] = __builtin_amdgcn_mfma_f32_16x16x32_bf16(alo, bh0, acc[0][2], 0, 0, 0);
            acc[1][0] = __builtin_amdgcn_mfma_f32_16x16x32_bf16(ahi, bh1, acc[1][0], 0, 0, 0);
            acc[1][1] = __builtin_amdgcn_mfma_f32_16x16x32_bf16(ahi, bl1, acc[1][1], 0, 0, 0);
            acc[1][2] = __builtin_amdgcn_mfma_f32_16x16x32_bf16(alo, bh1, acc[1][2], 0, 0, 0);
        }
        #pragma unroll
        for (int t2 = 0; t2 < 2; ++t2)
            #pragma unroll
            for (int r = 0; r < 4; ++r)
                part[kq][np * 2 + t2][(l >> 4) * 4 + r][lan15] =
                    acc[t2][0][r] + acc[t2][1][r] + acc[t2][2][r];
    }
    __syncthreads();

    if (tid < 256) {
        const int bb = tid >> 4, j2 = tid & 15;
        const int b = b0 + bb, hh = hh0 + j2;
        const float m0 = msk[bb][0], m1 = msk[bb][1], m2 = msk[bb][2];
        float g[6];
        #pragma unroll
        for (int q = 0; q < 6; ++q) {
            int gc = q * CH + hh;
            g[q] = part[0][q][bb][j2] + part[1][q][bb][j2]
                 + part[2][q][bb][j2] + part[3][q][bb][j2]
                 + Wx_b[gc] + m0 * Uh_b[gc] + m1 * Uh_b[CG_ + gc]
                            + m2 * Uh_b[2 * CG_ + gc];
        }
        float ig = 1.0f / (1.0f + expf(-g[0]));
        float og = 1.0f / (1.0f + expf(-g[1]));
        float ug = tanhf(g[2]);
        float c = ig * ug;
        if (m0 != 0.0f) c += (1.0f / (1.0f + expf(-g[3]))) * c_s[((size_t)cix[bb][0] * CB + b) * CH + hh];
        if (m1 != 0.0f) c += (1.0f / (1.0f + expf(-g[4]))) * c_s[((size_t)cix[bb][1] * CB + b) * CH + hh];
        if (m2 != 0.0f) c += (1.0f / (1.0f + expf(-g[5]))) * c_s[((size_t)cix[bb][2] * CB + b) * CH + hh];
        float h = og * tanhf(c);
        const size_t hx = ((size_t)t * CB + b) * CH + hh;
        u16 hb = f2bfu(h);
        h_hi[hx] = hb;
        h_lo[hx] = f2bfu(h - bfu2f(hb));
        c_s[hx] = c;
        if (t == CN - 1) out[(size_t)b * CH + hh] = h;
    }
}

__global__ void ws_report(float* out, int n, float val) {
    int i = blockIdx.x * blockDim.x + threadIdx.x;
    if (i < n) out[i] = val;
}

// ---------------------------------------------------------------------------
extern "C" void kernel_launch(void* const* d_in, const int* in_sizes, int n_in,
                              void* d_out, int out_size, void* d_ws, size_t ws_size,
                              hipStream_t stream) {
    float* outp = (float*)d_out;

    const int expect_sizes[7] = {65536, 196608, 8192000, 393216, 1536, 1179648, 4608};
    int bad = -1;
    if (n_in != 7) bad = 7;
    else for (int i = 0; i < 7; ++i) if (in_sizes[i] != expect_sizes[i]) { bad = i; break; }
    if (bad >= 0) {
        ws_report<<<(out_size + 255) / 256, 256, 0, stream>>>(outp, out_size, 1000.0f + bad);
        return;
    }

    const int*   node_ids = (const int*)d_in[0];
    const int*   children = (const int*)d_in[1];
    const float* emb      = (const float*)d_in[2];
    const float* Wx_w     = (const float*)d_in[3];
    const float* Wx_b     = (const float*)d_in[4];
    const float* Uh_w     = (const float*)d_in[5];
    const float* Uh_b     = (const float*)d_in[6];

    const size_t w_plane  = (size_t)CG_ * KTOT * 2;       //  3,145,728 B
    const size_t st_elems = (size_t)CN * CB * CH;         // 16,777,216
    const size_t flags_sz = 256 * 16 * sizeof(u32);       // 16 KB
    const size_t wl_sz    = (size_t)CB * CN * sizeof(u16);// 128 KB
    const size_t lvl_sz   = 256 * sizeof(u32);

    size_t off = 0;
    const size_t o_whi = off; off += w_plane;
    const size_t o_wlo = off; off += w_plane;
    const size_t o_hpk = off; off += st_elems * 4;
    const size_t o_cs  = off; off += st_elems * 4;
    const size_t o_flg = off; off += flags_sz;
    const size_t o_wl  = off; off += wl_sz;
    const size_t o_ls  = off; off += lvl_sz;
    const size_t o_lc  = off; off += lvl_sz;
    const size_t o_nl  = off; off += 64;
    const size_t need_lvl  = off;
    const size_t need_step = 2 * w_plane + st_elems * 2 * 2 + st_elems * 4;

    if (ws_size >= need_lvl) {
        char* w = (char*)d_ws;
        u16*   Whi = (u16*)(w + o_whi);
        u16*   Wlo = (u16*)(w + o_wlo);
        u32*   hpk = (u32*)(w + o_hpk);
        float* csb = (float*)(w + o_cs);
        u32*   flg = (u32*)(w + o_flg);
        u16*   wlp = (u16*)(w + o_wl);
        u32*   lsp = (u32*)(w + o_ls);
        u32*   lcp = (u32*)(w + o_lc);
        u32*   nlp = (u32*)(w + o_nl);

        prep_w<<<dim3(CG_), dim3(256), 0, stream>>>(Wx_w, Uh_w, Whi, Wlo);
        build_sched<<<dim3(1), dim3(256), 0, stream>>>(children, wlp, lsp, lcp, nlp);
        hipMemsetAsync(flg, 0, flags_sz, stream);

        void* args[] = { (void*)&node_ids, (void*)&children, (void*)&emb,
                         (void*)&Whi, (void*)&Wlo, (void*)&Wx_b, (void*)&Uh_b,
                         (void*)&hpk, (void*)&csb, (void*)&flg,
                         (void*)&wlp, (void*)&lsp, (void*)&lcp, (void*)&nlp,
                         (void*)&outp };
        hipError_t e = hipLaunchCooperativeKernel((const void*)tree_scan_lvl,
                                                  dim3(256), dim3(512), args, 0, stream);
        if (e == hipSuccess) return;
    }
    if (ws_size >= need_step) {
        char* w = (char*)d_ws;
        u16*   Whi = (u16*)w;
        u16*   Wlo = (u16*)(w + w_plane);
        u16*   hhi = (u16*)(w + 2 * w_plane);
        u16*   hlo = (u16*)(w + 2 * w_plane + st_elems * 2);
        float* csb = (float*)(w + 2 * w_plane + 2 * st_elems * 2);

        prep_w<<<dim3(CG_), dim3(256), 0, stream>>>(Wx_w, Uh_w, Whi, Wlo);
        for (int t = 0; t < CN; ++t)
            tree_step_mfma<<<dim3(256), dim3(768), 0, stream>>>(
                node_ids, children, emb, Whi, Wlo, Wx_b, Uh_b,
                hhi, hlo, csb, outp, t);
    } else {
        ws_report<<<(out_size + 255) / 256, 256, 0, stream>>>(
            outp, out_size, (float)(ws_size >> 20));
    }
}

// Round 24
// 1883.536 us; speedup vs baseline: 1.3880x; 1.0262x over previous
//
#include <hip/hip_runtime.h>
#include <hip/hip_bf16.h>

#define CB 256      // batch
#define CN 256      // nodes
#define CK 3        // children per node
#define CE 256      // embedding dim
#define CH 256      // hidden dim
#define CG_ 1536    // gates = 6*CH
#define KTOT 1024   // E + K*H
#define ROWS 32     // rows per chunk (r19/r22/r23-verified geometry)
#define ASTR 1032   // A row stride in u16 (2064 B)

typedef __attribute__((ext_vector_type(8))) short short8v;          // 8 bf16
typedef __attribute__((ext_vector_type(4))) float float4v;          // MFMA C/D
typedef __attribute__((ext_vector_type(4))) unsigned int uint4v;
typedef __attribute__((ext_vector_type(4))) unsigned short ushort4v;
typedef unsigned int u32;
typedef unsigned long long u64;
typedef unsigned short u16;

__device__ __forceinline__ u16 f2bfu(float v) {
    __hip_bfloat16 h = __float2bfloat16(v);
    return __builtin_bit_cast(u16, h);
}
__device__ __forceinline__ float bfu2f(u16 u) {
    __hip_bfloat16 h = __builtin_bit_cast(__hip_bfloat16, u);
    return __bfloat162float(h);
}

// ---------------------------------------------------------------------------
// r24 FUSED prep: one launch replaces {prep_w ; build_sched ; memset(flags)}
// (they were independent but serialized on the stream: ~176 us of the
// dur-vs-steady gap). Block 0: clear flags + build the level schedule with a
// 4-deep children prefetch pipeline (hides the uncoalesced gather latency
// behind the serial t-chain). Blocks 1..1536: the r17-verified fragment-order
// weight split. Same values/outputs as the separate kernels.
// ---------------------------------------------------------------------------
__global__ __launch_bounds__(256) void prep_fused(
    const float* __restrict__ Wx_w, const float* __restrict__ Uh_w,
    const int* __restrict__ children,
    u16* __restrict__ Whi, u16* __restrict__ Wlo,
    u16* __restrict__ wl, u32* __restrict__ lvl_start,
    u32* __restrict__ lvl_cnt, u32* __restrict__ nlev,
    u32* __restrict__ flags)
{
    __shared__ unsigned char lvl[CB][CN];   // 64 KB (block 0 only)
    __shared__ u32 cnt[CN];
    __shared__ u32 pos[CN];

    if (blockIdx.x != 0) {
        // ---- weight split (verified r17-r23) ----
        const int g    = blockIdx.x - 1;       // gate col 0..1535
        const int tile = g >> 4;
        const int gl   = g & 15;
        for (int k = threadIdx.x; k < KTOT; k += 256) {
            float w = (k < CE) ? Wx_w[(size_t)k * CG_ + g]
                               : Uh_w[(size_t)(k - CE) * CG_ + g];
            u16 hi = f2bfu(w);
            u16 lo = f2bfu(w - bfu2f(hi));
            int ci = k >> 5, kr = k & 31, lq = kr >> 3, j = kr & 7;
            size_t idx = ((size_t)(tile * 32 + ci) * 64 + lq * 16 + gl) * 8 + j;
            Whi[idx] = hi;
            Wlo[idx] = lo;
        }
        return;
    }

    // ---- block 0: flags clear + schedule build ----
    const int b = threadIdx.x;
    for (int i = b; i < 256 * 16; i += 256) flags[i] = 0;

    // 4-deep children prefetch pipeline over the serial t-chain
    int p0[4], p1[4], p2[4];
    #pragma unroll
    for (int p = 0; p < 4; ++p) {
        const int* cp = children + ((size_t)b * CN + p) * CK;
        p0[p] = cp[0]; p1[p] = cp[1]; p2[p] = cp[2];
    }
    for (int t = 0; t < CN; ++t) {
        const int s = t & 3;
        int c0 = p0[s], c1 = p1[s], c2 = p2[s];
        if (t + 4 < CN) {
            const int* cp = children + ((size_t)b * CN + (t + 4)) * CK;
            p0[s] = cp[0]; p1[s] = cp[1]; p2[s] = cp[2];
        }
        int lv = 0;
        if (c0 < t) { int cl = (int)lvl[b][c0] + 1; if (cl > lv) lv = cl; }
        if (c1 < t) { int cl = (int)lvl[b][c1] + 1; if (cl > lv) lv = cl; }
        if (c2 < t) { int cl = (int)lvl[b][c2] + 1; if (cl > lv) lv = cl; }
        lvl[b][t] = (unsigned char)lv;
    }
    cnt[b] = 0;
    __syncthreads();
    for (int t = 0; t < CN; ++t) atomicAdd(&cnt[lvl[b][t]], 1u);
    __syncthreads();
    if (b == 0) {
        u32 acc = 0, nl = 0;
        for (int L = 0; L < CN; ++L) {
            pos[L] = acc;
            if (cnt[L]) nl = (u32)L + 1;
            acc += cnt[L];
        }
        *nlev = nl;
    }
    __syncthreads();
    lvl_cnt[b]   = cnt[b];
    lvl_start[b] = pos[b];
    __syncthreads();                        // exports done before pos mutates
    for (int t = 0; t < CN; ++t) {
        int L = lvl[b][t];
        u32 p = atomicAdd(&pos[L], 1u);
        wl[p] = (u16)((b << 8) | t);
    }
}

// ---------------------------------------------------------------------------
// prep_w (standalone, for the fallback path only; verified r17-r23)
// ---------------------------------------------------------------------------
__global__ __launch_bounds__(256) void prep_w(
    const float* __restrict__ Wx_w, const float* __restrict__ Uh_w,
    u16* __restrict__ Whi, u16* __restrict__ Wlo)
{
    const int g    = blockIdx.x;
    const int tile = g >> 4;
    const int gl   = g & 15;
    for (int k = threadIdx.x; k < KTOT; k += 256) {
        float w = (k < CE) ? Wx_w[(size_t)k * CG_ + g]
                           : Uh_w[(size_t)(k - CE) * CG_ + g];
        u16 hi = f2bfu(w);
        u16 lo = f2bfu(w - bfu2f(hi));
        int ci = k >> 5, kr = k & 31, lq = kr >> 3, j = kr & 7;
        size_t idx = ((size_t)(tile * 32 + ci) * 64 + lq * 16 + gl) * 8 + j;
        Whi[idx] = hi;
        Wlo[idx] = lo;
    }
}

// ---------------------------------------------------------------------------
// r24 scan = r23 scan, byte-identical (best verified: 1757 us steady;
// MFMA phase measured at ~92% of the aggregate L2 bandwidth ceiling).
// ---------------------------------------------------------------------------
__global__ __launch_bounds__(512, 2) void tree_scan_lvl(
    const int* __restrict__ node_ids,          // [B][N]
    const int* __restrict__ children,          // [B][N][K]
    const float* __restrict__ emb,             // [V][E]
    const u16* __restrict__ Whi,               // fragment-ordered
    const u16* __restrict__ Wlo,               // fragment-ordered
    const float* __restrict__ Wx_b,            // [G]
    const float* __restrict__ Uh_b,            // [K][G]
    u32* __restrict__ h_pk,                    // [N][B][H] u32 (hi16|lo16)
    float* __restrict__ c_s,                   // [N][B][H] f32
    u32* __restrict__ flags,                   // [256*16], zeroed by prep
    const u16* __restrict__ wl,                // [65536]
    const u32* __restrict__ lvl_start,         // [256]
    const u32* __restrict__ lvl_cnt,           // [256]
    const u32* __restrict__ nlev_p,            // [1]
    float* __restrict__ out)                   // [B][H] f32
{
    const int tid = threadIdx.x;
    const int bid = blockIdx.x;
    const int xcd   = bid & 7;
    const int slice = xcd >> 2;                          // 0..1 (4 XCDs each)
    const int sub   = ((bid >> 3) << 2) | (bid & 3);     // 0..127
    const int hh0   = slice * 128;

    __shared__ u16   Ahi[ROWS][ASTR];          // 66,048 B
    __shared__ u16   Alo[ROWS][ASTR];          // 66,048 B
    __shared__ int   nid[ROWS], brow[ROWS], trow[ROWS];
    __shared__ unsigned char rval[ROWS];
    __shared__ float msk[ROWS][3];
    __shared__ int   cix[ROWS][3];

    const int wv    = tid >> 6;                // 0..7 = col-tile (ctq)
    const int l     = tid & 63;
    const int lan15 = l & 15;
    const int k8    = (l >> 4) * 8;            // k-offset inside A row (u16)
    const int hcol  = hh0 + wv * 16 + lan15;   // this lane's h column

    u32 bb[6];
    #pragma unroll
    for (int q = 0; q < 6; ++q)
        bb[q] = (u32)(q * 16 + slice * 8 + wv) * 16384u + (u32)l * 8u;

    float bwx[6], bu0[6], bu1[6], bu2[6];
    #pragma unroll
    for (int q = 0; q < 6; ++q) {
        int gc = q * CH + hcol;
        bwx[q] = Wx_b[gc];
        bu0[q] = Uh_b[gc];
        bu1[q] = Uh_b[CG_ + gc];
        bu2[q] = Uh_b[2 * CG_ + gc];
    }

    const u32 NL = *nlev_p;

    for (u32 L = 0; L < NL; ++L) {
        const u32 lcnt   = lvl_cnt[L];
        const u32 lst    = lvl_start[L];
        const u32 nchunk = (lcnt + ROWS - 1) / ROWS;

        for (u32 ck = sub; ck < nchunk; ck += 128) {
            if (tid < ROWS) {
                u32 i = ck * ROWS + (u32)tid;
                int valid = (i < lcnt);
                u16 e = valid ? wl[lst + i] : (u16)0;
                rval[tid] = (unsigned char)valid;
                int b_ = valid ? (e >> 8) : 0;
                int t_ = valid ? (e & 0xFF) : 0;
                brow[tid] = b_;
                trow[tid] = t_;
                nid[tid]  = node_ids[(size_t)b_ * CN + t_];
            }
            if (tid < ROWS * CK) {
                int lb = tid / 3, k = tid - lb * 3;
                u32 i = ck * ROWS + (u32)lb;
                int valid = (i < lcnt);
                u16 e = valid ? wl[lst + i] : (u16)0;
                int b_ = valid ? (e >> 8) : 0;
                int t_ = valid ? (e & 0xFF) : 0;
                int raw = children[((size_t)b_ * CN + t_) * CK + k];
                int v = (raw < t_) && valid;
                msk[lb][k] = v ? 1.0f : 0.0f;
                cix[lb][k] = v ? raw : 0;
            }
            __syncthreads();

            // stage x: 32 rows x 64 float4; split hi/lo in-register
            for (int idx = tid; idx < ROWS * 64; idx += 512) {
                int row = idx >> 6, c4 = idx & 63;
                float4v v = *(const float4v*)(emb + (size_t)nid[row] * CE + c4 * 4);
                ushort4v h4, l4;
                #pragma unroll
                for (int j = 0; j < 4; ++j) {
                    u16 hb = f2bfu(v[j]);
                    h4[j] = hb;
                    l4[j] = f2bfu(v[j] - bfu2f(hb));
                }
                *(ushort4v*)&Ahi[row][c4 * 4] = h4;
                *(ushort4v*)&Alo[row][c4 * 4] = l4;
            }
            // stage h: split hi/lo while staging; plain cacheable loads
            for (int idx = tid; idx < ROWS * CK * 64; idx += 512) {
                int r  = idx >> 6;
                int ch = idx & 63;
                int row = r / 3, k = r - row * 3;
                uint4v v = (uint4v){0u, 0u, 0u, 0u};
                if (msk[row][k] != 0.0f) {
                    const uint4v* src = (const uint4v*)(h_pk
                        + ((size_t)cix[row][k] * CB + brow[row]) * CH + 4 * ch);
                    v = *src;
                }
                ushort4v h4, l4;
                #pragma unroll
                for (int j = 0; j < 4; ++j) {
                    h4[j] = (u16)(v[j] >> 16);
                    l4[j] = (u16)(v[j] & 0xffffu);
                }
                int cc = CE + k * CH + 4 * ch;
                *(ushort4v*)&Ahi[row][cc] = h4;
                *(ushort4v*)&Alo[row][cc] = l4;
            }
            __syncthreads();

            // c_s child prefetch (hidden under MFMA; r23-verified)
            float cpre[2][4][3];
            #pragma unroll
            for (int rg = 0; rg < 2; ++rg)
                #pragma unroll
                for (int r = 0; r < 4; ++r) {
                    const int row = rg * 16 + (l >> 4) * 4 + r;
                    const int b = brow[row];
                    #pragma unroll
                    for (int k = 0; k < 3; ++k)
                        cpre[rg][r][k] =
                            c_s[((size_t)cix[row][k] * CB + b) * CH + hcol];
                }

            // MFMA bf16x3: B loaded once per (ci,q), reused for both rg
            float4v accH[2][6], accL[2][6];
            #pragma unroll
            for (int rg = 0; rg < 2; ++rg)
                #pragma unroll
                for (int q = 0; q < 6; ++q) {
                    accH[rg][q] = (float4v){0.f, 0.f, 0.f, 0.f};
                    accL[rg][q] = (float4v){0.f, 0.f, 0.f, 0.f};
                }
            #pragma unroll 2
            for (int ci = 0; ci < 32; ++ci) {
                short8v ahi0 = *(const short8v*)&Ahi[lan15][ci * 32 + k8];
                short8v alo0 = *(const short8v*)&Alo[lan15][ci * 32 + k8];
                short8v ahi1 = *(const short8v*)&Ahi[16 + lan15][ci * 32 + k8];
                short8v alo1 = *(const short8v*)&Alo[16 + lan15][ci * 32 + k8];
                #pragma unroll
                for (int q = 0; q < 6; ++q) {
                    short8v bh = *(const short8v*)(Whi + bb[q] + ci * 512);
                    short8v bl = *(const short8v*)(Wlo + bb[q] + ci * 512);
                    accH[0][q] = __builtin_amdgcn_mfma_f32_16x16x32_bf16(ahi0, bh, accH[0][q], 0, 0, 0);
                    accL[0][q] = __builtin_amdgcn_mfma_f32_16x16x32_bf16(ahi0, bl, accL[0][q], 0, 0, 0);
                    accL[0][q] = __builtin_amdgcn_mfma_f32_16x16x32_bf16(alo0, bh, accL[0][q], 0, 0, 0);
                    accH[1][q] = __builtin_amdgcn_mfma_f32_16x16x32_bf16(ahi1, bh, accH[1][q], 0, 0, 0);
                    accL[1][q] = __builtin_amdgcn_mfma_f32_16x16x32_bf16(ahi1, bl, accL[1][q], 0, 0, 0);
                    accL[1][q] = __builtin_amdgcn_mfma_f32_16x16x32_bf16(alo1, bh, accL[1][q], 0, 0, 0);
                }
            }

            // fused cell phase, in-lane on D-layout (col=l&15, row=(l>>4)*4+r)
            #pragma unroll
            for (int rg = 0; rg < 2; ++rg)
            #pragma unroll
            for (int r = 0; r < 4; ++r) {
                const int row = rg * 16 + (l >> 4) * 4 + r;
                if (rval[row]) {
                    const int b = brow[row], t_ = trow[row];
                    const float m0 = msk[row][0], m1 = msk[row][1], m2 = msk[row][2];
                    float g[6];
                    #pragma unroll
                    for (int q = 0; q < 6; ++q)
                        g[q] = accH[rg][q][r] + accL[rg][q][r]
                             + bwx[q] + m0 * bu0[q] + m1 * bu1[q] + m2 * bu2[q];
                    float ig = 1.0f / (1.0f + expf(-g[0]));
                    float og = 1.0f / (1.0f + expf(-g[1]));
                    float ug = tanhf(g[2]);
                    float c = ig * ug;
                    if (m0 != 0.0f) c += (1.0f / (1.0f + expf(-g[3]))) * cpre[rg][r][0];
                    if (m1 != 0.0f) c += (1.0f / (1.0f + expf(-g[4]))) * cpre[rg][r][1];
                    if (m2 != 0.0f) c += (1.0f / (1.0f + expf(-g[5]))) * cpre[rg][r][2];
                    float h = og * tanhf(c);
                    const size_t hx = ((size_t)t_ * CB + b) * CH + hcol;
                    u16 hb = f2bfu(h);
                    u32 hp = ((u32)hb << 16) | (u32)f2bfu(h - bfu2f(hb));
                    __hip_atomic_store(&h_pk[hx], hp, __ATOMIC_RELAXED, __HIP_MEMORY_SCOPE_AGENT);
                    __hip_atomic_store(&c_s[hx], c, __ATOMIC_RELAXED, __HIP_MEMORY_SCOPE_AGENT);
                    if (t_ == CN - 1) out[(size_t)b * CH + hcol] = h;
                }
            }
            __syncthreads();                   // LDS free before next chunk
        }

        if (L == NL - 1) break;

        // ---- light grid barrier per level (r12/r14-r23 verified) ----
        __syncthreads();
        if (tid == 0)
            __hip_atomic_store(&flags[bid * 16], L + 1,
                               __ATOMIC_RELAXED, __HIP_MEMORY_SCOPE_AGENT);
        for (;;) {
            int ok = 1;
            if (tid < 256)
                ok = (__hip_atomic_load(&flags[tid * 16], __ATOMIC_RELAXED,
                                        __HIP_MEMORY_SCOPE_AGENT) >= L + 1);
            if (__syncthreads_and(ok)) break;
            __builtin_amdgcn_s_sleep(2);
        }
    }
}

// ---------------------------------------------------------------------------
// Fallback: per-step kernel with fragment-ordered B (r17-r23-verified backup).
// ---------------------------------------------------------------------------
__global__ __launch_bounds__(768) void tree_step_mfma(
    const int* __restrict__ node_ids, const int* __restrict__ children,
    const float* __restrict__ emb,
    const u16* __restrict__ Whi, const u16* __restrict__ Wlo,
    const float* __restrict__ Wx_b, const float* __restrict__ Uh_b,
    u16* __restrict__ h_hi, u16* __restrict__ h_lo,
    float* __restrict__ c_s, float* __restrict__ out, const int t)
{
    const int tid = threadIdx.x;
    const int xcd  = blockIdx.x & 7;
    const int bidx = blockIdx.x >> 3;
    const int hi   = xcd * 2 + (bidx & 1);
    const int bi   = bidx >> 1;
    const int b0   = bi * 16;
    const int hh0  = hi * 16;

    __shared__ u16   Ahi[16][KTOT + 8];
    __shared__ u16   Alo[16][KTOT + 8];
    __shared__ float part[4][6][16][17];
    __shared__ int   nid[16];
    __shared__ float msk[16][3];
    __shared__ int   cix[16][3];

    const int wv    = tid >> 6;
    const int l     = tid & 63;
    const int np    = wv % 3;
    const int kq    = wv / 3;
    const int lan15 = l & 15;
    const int k8    = (l >> 4) * 8;

    if (tid < 16) nid[tid] = node_ids[(size_t)(b0 + tid) * CN + t];
    if (tid < 48) {
        int lb = tid / 3, k = tid - lb * 3;
        int raw = children[((size_t)(b0 + lb) * CN + t) * CK + k];
        int v = raw < t;
        msk[lb][k] = v ? 1.0f : 0.0f;
        cix[lb][k] = v ? raw : 0;
    }
    __syncthreads();

    for (int idx = tid; idx < 1024; idx += 768) {
        int lb = idx >> 6, c4 = idx & 63;
        float4v v = *(const float4v*)(emb + (size_t)nid[lb] * CE + c4 * 4);
        ushort4v h4, l4;
        #pragma unroll
        for (int j = 0; j < 4; ++j) {
            u16 hb = f2bfu(v[j]);
            h4[j] = hb;
            l4[j] = f2bfu(v[j] - bfu2f(hb));
        }
        *(ushort4v*)&Ahi[lb][c4 * 4] = h4;
        *(ushort4v*)&Alo[lb][c4 * 4] = l4;
    }
    for (int idx = tid; idx < 3072; idx += 768) {
        int r  = idx >> 6;
        int c  = idx & 63;
        int pl = c >> 5;
        int ch = c & 31;
        int lb = r / 3, k = r - lb * 3;
        uint4v val = (uint4v){0u, 0u, 0u, 0u};
        if (msk[lb][k] != 0.0f) {
            const u16* src = (pl ? h_lo : h_hi)
                + ((size_t)cix[lb][k] * CB + (b0 + lb)) * CH + ch * 8;
            val = *(const uint4v*)src;
        }
        u16* dst = (pl ? &Alo[lb][CE + k * CH + ch * 8]
                       : &Ahi[lb][CE + k * CH + ch * 8]);
        *(uint4v*)dst = val;
    }
    __syncthreads();

    {
        float4v acc[2][3];
        #pragma unroll
        for (int a = 0; a < 2; ++a)
            #pragma unroll
            for (int b2 = 0; b2 < 3; ++b2)
                acc[a][b2] = (float4v){0.f, 0.f, 0.f, 0.f};
        u32 fb0 = (u32)((np * 2 + 0) * 16 + hi) * 16384u + (u32)l * 8u;
        u32 fb1 = (u32)((np * 2 + 1) * 16 + hi) * 16384u + (u32)l * 8u;
        #pragma unroll
        for (int ci = 0; ci < 8; ++ci) {
            const int kb = (kq * 8 + ci) * 32 + k8;
            const u32 fo = (u32)(kq * 8 + ci) * 512u;
            short8v ahi = *(const short8v*)&Ahi[lan15][kb];
            short8v alo = *(const short8v*)&Alo[lan15][kb];
            short8v bh0 = *(const short8v*)(Whi + fb0 + fo);
            short8v bh1 = *(const short8v*)(Whi + fb1 + fo);
            short8v bl0 = *(const short8v*)(Wlo + fb0 + fo);
            short8v bl1 = *(const short8v*)(Wlo + fb1 + fo);
            acc[0][0] = __builtin_amdgcn_mfma_f32_16x16x32_bf16(ahi, bh0, acc[0][0], 0, 0, 0);
            acc[0][1] = __builtin_amdgcn_mfma_f32_16x16x32_bf16(ahi, bl0, acc[0][1], 0, 0, 0);
            acc[0][2] = __builtin_amdgcn_mfma_f32_16x16x32_bf16(alo, bh0, acc[0][2], 0, 0, 0);
            acc[1][0] = __builtin_amdgcn_mfma_f32_16x16x32_bf16(ahi, bh1, acc[1][0], 0, 0, 0);
            acc[1][1] = __builtin_amdgcn_mfma_f32_16x16x32_bf16(ahi, bl1, acc[1][1], 0, 0, 0);
            acc[1][2] = __builtin_amdgcn_mfma_f32_16x16x32_bf16(alo, bh1, acc[1][2], 0, 0, 0);
        }
        #pragma unroll
        for (int t2 = 0; t2 < 2; ++t2)
            #pragma unroll
            for (int r = 0; r < 4; ++r)
                part[kq][np * 2 + t2][(l >> 4) * 4 + r][lan15] =
                    acc[t2][0][r] + acc[t2][1][r] + acc[t2][2][r];
    }
    __syncthreads();

    if (tid < 256) {
        const int bb = tid >> 4, j2 = tid & 15;
        const int b = b0 + bb, hh = hh0 + j2;
        const float m0 = msk[bb][0], m1 = msk[bb][1], m2 = msk[bb][2];
        float g[6];
        #pragma unroll
        for (int q = 0; q < 6; ++q) {
            int gc = q * CH + hh;
            g[q] = part[0][q][bb][j2] + part[1][q][bb][j2]
                 + part[2][q][bb][j2] + part[3][q][bb][j2]
                 + Wx_b[gc] + m0 * Uh_b[gc] + m1 * Uh_b[CG_ + gc]
                            + m2 * Uh_b[2 * CG_ + gc];
        }
        float ig = 1.0f / (1.0f + expf(-g[0]));
        float og = 1.0f / (1.0f + expf(-g[1]));
        float ug = tanhf(g[2]);
        float c = ig * ug;
        if (m0 != 0.0f) c += (1.0f / (1.0f + expf(-g[3]))) * c_s[((size_t)cix[bb][0] * CB + b) * CH + hh];
        if (m1 != 0.0f) c += (1.0f / (1.0f + expf(-g[4]))) * c_s[((size_t)cix[bb][1] * CB + b) * CH + hh];
        if (m2 != 0.0f) c += (1.0f / (1.0f + expf(-g[5]))) * c_s[((size_t)cix[bb][2] * CB + b) * CH + hh];
        float h = og * tanhf(c);
        const size_t hx = ((size_t)t * CB + b) * CH + hh;
        u16 hb = f2bfu(h);
        h_hi[hx] = hb;
        h_lo[hx] = f2bfu(h - bfu2f(hb));
        c_s[hx] = c;
        if (t == CN - 1) out[(size_t)b * CH + hh] = h;
    }
}

__global__ void ws_report(float* out, int n, float val) {
    int i = blockIdx.x * blockDim.x + threadIdx.x;
    if (i < n) out[i] = val;
}

// ---------------------------------------------------------------------------
extern "C" void kernel_launch(void* const* d_in, const int* in_sizes, int n_in,
                              void* d_out, int out_size, void* d_ws, size_t ws_size,
                              hipStream_t stream) {
    float* outp = (float*)d_out;

    const int expect_sizes[7] = {65536, 196608, 8192000, 393216, 1536, 1179648, 4608};
    int bad = -1;
    if (n_in != 7) bad = 7;
    else for (int i = 0; i < 7; ++i) if (in_sizes[i] != expect_sizes[i]) { bad = i; break; }
    if (bad >= 0) {
        ws_report<<<(out_size + 255) / 256, 256, 0, stream>>>(outp, out_size, 1000.0f + bad);
        return;
    }

    const int*   node_ids = (const int*)d_in[0];
    const int*   children = (const int*)d_in[1];
    const float* emb      = (const float*)d_in[2];
    const float* Wx_w     = (const float*)d_in[3];
    const float* Wx_b     = (const float*)d_in[4];
    const float* Uh_w     = (const float*)d_in[5];
    const float* Uh_b     = (const float*)d_in[6];

    const size_t w_plane  = (size_t)CG_ * KTOT * 2;       //  3,145,728 B
    const size_t st_elems = (size_t)CN * CB * CH;         // 16,777,216
    const size_t flags_sz = 256 * 16 * sizeof(u32);       // 16 KB
    const size_t wl_sz    = (size_t)CB * CN * sizeof(u16);// 128 KB
    const size_t lvl_sz   = 256 * sizeof(u32);

    size_t off = 0;
    const size_t o_whi = off; off += w_plane;
    const size_t o_wlo = off; off += w_plane;
    const size_t o_hpk = off; off += st_elems * 4;
    const size_t o_cs  = off; off += st_elems * 4;
    const size_t o_flg = off; off += flags_sz;
    const size_t o_wl  = off; off += wl_sz;
    const size_t o_ls  = off; off += lvl_sz;
    const size_t o_lc  = off; off += lvl_sz;
    const size_t o_nl  = off; off += 64;
    const size_t need_lvl  = off;
    const size_t need_step = 2 * w_plane + st_elems * 2 * 2 + st_elems * 4;

    if (ws_size >= need_lvl) {
        char* w = (char*)d_ws;
        u16*   Whi = (u16*)(w + o_whi);
        u16*   Wlo = (u16*)(w + o_wlo);
        u32*   hpk = (u32*)(w + o_hpk);
        float* csb = (float*)(w + o_cs);
        u32*   flg = (u32*)(w + o_flg);
        u16*   wlp = (u16*)(w + o_wl);
        u32*   lsp = (u32*)(w + o_ls);
        u32*   lcp = (u32*)(w + o_lc);
        u32*   nlp = (u32*)(w + o_nl);

        // one fused prep launch: weight split (blocks 1..1536) runs
        // CONCURRENTLY with schedule build + flags clear (block 0)
        prep_fused<<<dim3(CG_ + 1), dim3(256), 0, stream>>>(
            Wx_w, Uh_w, children, Whi, Wlo, wlp, lsp, lcp, nlp, flg);

        void* args[] = { (void*)&node_ids, (void*)&children, (void*)&emb,
                         (void*)&Whi, (void*)&Wlo, (void*)&Wx_b, (void*)&Uh_b,
                         (void*)&hpk, (void*)&csb, (void*)&flg,
                         (void*)&wlp, (void*)&lsp, (void*)&lcp, (void*)&nlp,
                         (void*)&outp };
        hipError_t e = hipLaunchCooperativeKernel((const void*)tree_scan_lvl,
                                                  dim3(256), dim3(512), args, 0, stream);
        if (e == hipSuccess) return;
    }
    if (ws_size >= need_step) {
        char* w = (char*)d_ws;
        u16*   Whi = (u16*)w;
        u16*   Wlo = (u16*)(w + w_plane);
        u16*   hhi = (u16*)(w + 2 * w_plane);
        u16*   hlo = (u16*)(w + 2 * w_plane + st_elems * 2);
        float* csb = (float*)(w + 2 * w_plane + 2 * st_elems * 2);

        prep_w<<<dim3(CG_), dim3(256), 0, stream>>>(Wx_w, Uh_w, Whi, Wlo);
        for (int t = 0; t < CN; ++t)
            tree_step_mfma<<<dim3(256), dim3(768), 0, stream>>>(
                node_ids, children, emb, Whi, Wlo, Wx_b, Uh_b,
                hhi, hlo, csb, outp, t);
    } else {
        ws_report<<<(out_size + 255) / 256, 256, 0, stream>>>(
            outp, out_size, (float)(ws_size >> 20));
    }
}